// Round 1
// baseline (803.724 us; speedup 1.0000x reference)
//
#include <hip/hip_runtime.h>
#include <hip/hip_bf16.h>
#include <math.h>

#define F_IN 512
#define HOUT 64      // HEADS*C1
#define HEADS 8
#define C1 8
#define NCLS 40
#define NEG 0.2f

// ---------------- CSR build ----------------

__global__ void deg_k(const int* __restrict__ ei, int* __restrict__ deg, int E, int n) {
    int t = blockIdx.x * blockDim.x + threadIdx.x;
    if (t >= E + n) return;
    int d = (t < E) ? ei[E + t] : (t - E);
    atomicAdd(&deg[d], 1);
}

__global__ __launch_bounds__(256) void scan1_k(const int* __restrict__ deg, int* __restrict__ incl,
                                               int* __restrict__ bsum, int n) {
    __shared__ int wsum[4];
    int tid = threadIdx.x;
    int idx0 = blockIdx.x * 1024 + tid * 4;
    int v[4]; int s = 0;
#pragma unroll
    for (int j = 0; j < 4; ++j) { int id = idx0 + j; v[j] = (id < n) ? deg[id] : 0; s += v[j]; }
    int lane = tid & 63, w = tid >> 6;
    int ss = s;
#pragma unroll
    for (int off = 1; off < 64; off <<= 1) { int t2 = __shfl_up(ss, off); if (lane >= off) ss += t2; }
    if (lane == 63) wsum[w] = ss;
    __syncthreads();
    int woff = 0;
    for (int j = 0; j < w; ++j) woff += wsum[j];
    int run = woff + ss - s;   // exclusive prefix for this thread
#pragma unroll
    for (int j = 0; j < 4; ++j) { run += v[j]; int id = idx0 + j; if (id < n) incl[id] = run; }
    if (tid == 255) bsum[blockIdx.x] = woff + ss;
}

__global__ __launch_bounds__(128) void scan2_k(const int* __restrict__ bsum, int* __restrict__ boff,
                                               int* __restrict__ rowptr, int nb, int n) {
    __shared__ int ws0;
    int tid = threadIdx.x;
    int v = (tid < nb) ? bsum[tid] : 0;
    int lane = tid & 63, w = tid >> 6;
    int ss = v;
#pragma unroll
    for (int off = 1; off < 64; off <<= 1) { int t2 = __shfl_up(ss, off); if (lane >= off) ss += t2; }
    if (w == 0 && lane == 63) ws0 = ss;
    __syncthreads();
    if (w == 1) ss += ws0;
    if (tid < nb) boff[tid] = ss - v;
    if (tid == nb - 1) rowptr[n] = ss;
}

__global__ void scan3_k(const int* __restrict__ incl, const int* __restrict__ deg,
                        const int* __restrict__ boff, int* __restrict__ rowptr,
                        int* __restrict__ cursor, int n) {
    int i = blockIdx.x * blockDim.x + threadIdx.x;
    if (i >= n) return;
    int r = incl[i] - deg[i] + boff[i >> 10];
    rowptr[i] = r;
    cursor[i] = r;
}

__global__ void scatter_k(const int* __restrict__ ei, int* __restrict__ cursor,
                          int* __restrict__ col_src, int E, int n) {
    int t = blockIdx.x * blockDim.x + threadIdx.x;
    if (t >= E + n) return;
    int s, d;
    if (t < E) { s = ei[t]; d = ei[E + t]; } else { s = t - E; d = t - E; }
    int pos = atomicAdd(&cursor[d], 1);
    col_src[pos] = s;
}

// ---------------- Layer 1 GEMM: h1[n,64] = x[n,512] @ W1[512,64] ----------------
// 128x64 tile, BK=32, 256 threads, 8x4 microtile. A stored K-major in LDS.

__global__ __launch_bounds__(256) void gemm1_k(const float* __restrict__ x, const float* __restrict__ W,
                                               float* __restrict__ h, int n) {
    __shared__ float As[32][132];   // [kk][row], stride 132 keeps 16B alignment, spreads banks
    __shared__ float Bs[32][64];
    int tid = threadIdx.x;
    int row0 = blockIdx.x * 128;
    int tx = tid & 15, ty = tid >> 4;
    float acc[8][4] = {};
    for (int k0 = 0; k0 < F_IN; k0 += 32) {
#pragma unroll
        for (int j = 0; j < 4; ++j) {
            int idx = tid + j * 256;        // 0..1023
            int r = idx >> 3;               // 0..127
            int c4 = (idx & 7) << 2;        // 0..28
            int gr = row0 + r;
            float4 v = (gr < n) ? *(const float4*)&x[(size_t)gr * F_IN + k0 + c4]
                                : make_float4(0.f, 0.f, 0.f, 0.f);
            As[c4 + 0][r] = v.x; As[c4 + 1][r] = v.y; As[c4 + 2][r] = v.z; As[c4 + 3][r] = v.w;
        }
#pragma unroll
        for (int j = 0; j < 2; ++j) {
            int idx = tid + j * 256;        // 0..511
            int r = idx >> 4;               // 0..31
            int c4 = (idx & 15) << 2;       // 0..60
            *(float4*)&Bs[r][c4] = *(const float4*)&W[(size_t)(k0 + r) * HOUT + c4];
        }
        __syncthreads();
#pragma unroll
        for (int kk = 0; kk < 32; ++kk) {
            float4 a0 = *(const float4*)&As[kk][ty * 8];
            float4 a1 = *(const float4*)&As[kk][ty * 8 + 4];
            float4 bv = *(const float4*)&Bs[kk][tx * 4];
            float a[8] = {a0.x, a0.y, a0.z, a0.w, a1.x, a1.y, a1.z, a1.w};
            float b[4] = {bv.x, bv.y, bv.z, bv.w};
#pragma unroll
            for (int r = 0; r < 8; ++r)
#pragma unroll
                for (int c = 0; c < 4; ++c) acc[r][c] += a[r] * b[c];
        }
        __syncthreads();
    }
#pragma unroll
    for (int r = 0; r < 8; ++r) {
        int gr = row0 + ty * 8 + r;
        if (gr < n)
            *(float4*)&h[(size_t)gr * HOUT + tx * 4] =
                make_float4(acc[r][0], acc[r][1], acc[r][2], acc[r][3]);
    }
}

// ---------------- attention dot products layer 1: a_s/a_d [n,8] ----------------

__global__ void att1_k(const float* __restrict__ h1, const float* __restrict__ asw,
                       const float* __restrict__ adw, float* __restrict__ as1,
                       float* __restrict__ ad1, int n) {
    int t = blockIdx.x * blockDim.x + threadIdx.x;
    if (t >= n * HEADS) return;
    int hd = t & 7;
    const float* hp = h1 + (size_t)(t >> 3) * HOUT + hd * C1;
    float4 h0 = *(const float4*)hp, h1v = *(const float4*)(hp + 4);
    float4 a0 = *(const float4*)(asw + hd * C1), a1 = *(const float4*)(asw + hd * C1 + 4);
    float4 d0 = *(const float4*)(adw + hd * C1), d1 = *(const float4*)(adw + hd * C1 + 4);
    as1[t] = h0.x*a0.x + h0.y*a0.y + h0.z*a0.z + h0.w*a0.w
           + h1v.x*a1.x + h1v.y*a1.y + h1v.z*a1.z + h1v.w*a1.w;
    ad1[t] = h0.x*d0.x + h0.y*d0.y + h0.z*d0.z + h0.w*d0.w
           + h1v.x*d1.x + h1v.y*d1.y + h1v.z*d1.z + h1v.w*d1.w;
}

// ---------------- layer-1 aggregation: wave per dst node, online softmax ----------------

__global__ __launch_bounds__(256) void l1agg_k(const float* __restrict__ h1, const float* __restrict__ as1,
                                               const float* __restrict__ ad1, const float* __restrict__ b1,
                                               const int* __restrict__ rowptr, const int* __restrict__ col,
                                               float* __restrict__ hact, int n) {
    int lane = threadIdx.x & 63;
    int node = blockIdx.x * 4 + (threadIdx.x >> 6);
    if (node >= n) return;
    int hd = lane >> 3;
    float ad = ad1[node * HEADS + hd];
    int st = rowptr[node], en = rowptr[node + 1];
    float m = -1e30f, den = 0.f, acc = 0.f;
    for (int e = st; e < en; ++e) {
        int s = col[e];
        float e0 = as1[s * HEADS + hd] + ad;
        float ee = e0 >= 0.f ? e0 : NEG * e0;
        float hv = h1[(size_t)s * HOUT + lane];
        float mn = fmaxf(m, ee);
        float sc = __expf(m - mn), p = __expf(ee - mn);
        den = den * sc + p;
        acc = acc * sc + p * hv;
        m = mn;
    }
    float o = acc / (den + 1e-16f) + b1[lane];
    hact[(size_t)node * HOUT + lane] = o > 0.f ? o : expm1f(o);   // ELU
}

// ---------------- layer-2 GEMM (64->40) + attention dots, wave per node ----------------

__global__ __launch_bounds__(256) void g2_k(const float* __restrict__ hact, const float* __restrict__ W2,
                                            const float* __restrict__ asw, const float* __restrict__ adw,
                                            float* __restrict__ h2, float* __restrict__ as2,
                                            float* __restrict__ ad2, int n) {
    __shared__ float W2s[HOUT * NCLS];
    for (int t = threadIdx.x; t < HOUT * NCLS; t += 256) W2s[t] = W2[t];
    __syncthreads();
    int lane = threadIdx.x & 63;
    int node = blockIdx.x * 4 + (threadIdx.x >> 6);
    if (node >= n) return;
    float hreg = hact[(size_t)node * HOUT + lane];
    int cc = lane < NCLS ? lane : 0;
    float o = 0.f;
#pragma unroll
    for (int k = 0; k < HOUT; ++k) {
        float hk = __shfl(hreg, k);
        o += hk * W2s[k * NCLS + cc];
    }
    float av = lane < NCLS ? o * asw[lane] : 0.f;
    float dv = lane < NCLS ? o * adw[lane] : 0.f;
#pragma unroll
    for (int off = 32; off > 0; off >>= 1) {
        av += __shfl_xor(av, off);
        dv += __shfl_xor(dv, off);
    }
    if (lane < NCLS) h2[(size_t)node * NCLS + lane] = o;
    if (lane == 0) { as2[node] = av; ad2[node] = dv; }
}

// ---------------- layer-2 aggregation + log_softmax, wave per node ----------------

__global__ __launch_bounds__(256) void l2agg_k(const float* __restrict__ h2, const float* __restrict__ as2,
                                               const float* __restrict__ ad2, const float* __restrict__ b2,
                                               const int* __restrict__ rowptr, const int* __restrict__ col,
                                               float* __restrict__ out, int n) {
    int lane = threadIdx.x & 63;
    int node = blockIdx.x * 4 + (threadIdx.x >> 6);
    if (node >= n) return;
    bool act = lane < NCLS;
    float ad = ad2[node];
    int st = rowptr[node], en = rowptr[node + 1];
    float m = -1e30f, den = 0.f, acc = 0.f;
    for (int e = st; e < en; ++e) {
        int s = col[e];
        float e0 = as2[s] + ad;
        float ee = e0 >= 0.f ? e0 : NEG * e0;
        float hv = act ? h2[(size_t)s * NCLS + lane] : 0.f;
        float mn = fmaxf(m, ee);
        float sc = __expf(m - mn), p = __expf(ee - mn);
        den = den * sc + p;
        acc = acc * sc + p * hv;
        m = mn;
    }
    float z = act ? (acc / (den + 1e-16f) + b2[lane]) : -1e30f;
    float zm = z;
#pragma unroll
    for (int off = 32; off > 0; off >>= 1) zm = fmaxf(zm, __shfl_xor(zm, off));
    float ex = act ? __expf(z - zm) : 0.f;
    float ss = ex;
#pragma unroll
    for (int off = 32; off > 0; off >>= 1) ss += __shfl_xor(ss, off);
    if (act) out[(size_t)node * NCLS + lane] = z - zm - logf(ss);
}

// ---------------- host ----------------

extern "C" void kernel_launch(void* const* d_in, const int* in_sizes, int n_in,
                              void* d_out, int out_size, void* d_ws, size_t ws_size,
                              hipStream_t stream) {
    const float* x    = (const float*)d_in[0];
    const int*   ei   = (const int*)d_in[1];
    const float* W1   = (const float*)d_in[2];
    const float* asw1 = (const float*)d_in[3];
    const float* adw1 = (const float*)d_in[4];
    const float* b1   = (const float*)d_in[5];
    const float* W2   = (const float*)d_in[6];
    const float* asw2 = (const float*)d_in[7];
    const float* adw2 = (const float*)d_in[8];
    const float* b2   = (const float*)d_in[9];
    float* out = (float*)d_out;

    const int n = in_sizes[0] / F_IN;          // 100000
    const int E = in_sizes[1] / 2;             // 1600000
    const int Etot = E + n;

    char* ws = (char*)d_ws;
    size_t off = 0;
    auto alloc = [&](size_t bytes) -> void* {
        void* p = ws + off;
        off = (off + bytes + 255) & ~(size_t)255;
        return p;
    };
    int*   deg    = (int*)alloc((size_t)n * 4);
    int*   cursor = (int*)alloc((size_t)n * 4);
    int*   rowptr = (int*)alloc((size_t)(n + 1) * 4);
    int*   incl   = (int*)alloc((size_t)n * 4);
    int*   bsum   = (int*)alloc(512);
    int*   boff   = (int*)alloc(512);
    int*   col    = (int*)alloc((size_t)Etot * 4);
    float* h1     = (float*)alloc((size_t)n * HOUT * 4);   // reused for h2/as2/ad2 after l1agg
    float* as1    = (float*)alloc((size_t)n * HEADS * 4);
    float* ad1    = (float*)alloc((size_t)n * HEADS * 4);
    float* hact   = (float*)alloc((size_t)n * HOUT * 4);
    // aliases into h1's region (h1 is dead after l1agg_k; 42n floats <= 64n floats)
    float* h2  = h1;
    float* as2 = h1 + (size_t)n * NCLS;
    float* ad2 = h1 + (size_t)n * (NCLS + 1);

    const int nb = (n + 1023) / 1024;

    hipMemsetAsync(deg, 0, (size_t)n * 4, stream);
    deg_k<<<(Etot + 255) / 256, 256, 0, stream>>>(ei, deg, E, n);
    scan1_k<<<nb, 256, 0, stream>>>(deg, incl, bsum, n);
    scan2_k<<<1, 128, 0, stream>>>(bsum, boff, rowptr, nb, n);
    scan3_k<<<(n + 255) / 256, 256, 0, stream>>>(incl, deg, boff, rowptr, cursor, n);
    scatter_k<<<(Etot + 255) / 256, 256, 0, stream>>>(ei, cursor, col, E, n);

    gemm1_k<<<(n + 127) / 128, 256, 0, stream>>>(x, W1, h1, n);
    att1_k<<<(n * HEADS + 255) / 256, 256, 0, stream>>>(h1, asw1, adw1, as1, ad1, n);
    l1agg_k<<<(n + 3) / 4, 256, 0, stream>>>(h1, as1, ad1, b1, rowptr, col, hact, n);
    g2_k<<<(n + 3) / 4, 256, 0, stream>>>(hact, W2, asw2, adw2, h2, as2, ad2, n);
    l2agg_k<<<(n + 3) / 4, 256, 0, stream>>>(h2, as2, ad2, b2, rowptr, col, out, n);
}

// Round 2
// 728.584 us; speedup vs baseline: 1.1031x; 1.1031x over previous
//
#include <hip/hip_runtime.h>
#include <hip/hip_bf16.h>
#include <math.h>

#define F_IN 512
#define HOUT 64      // HEADS*C1
#define HEADS 8
#define C1 8
#define NCLS 40
#define NEG 0.2f

// ---------------- CSR build ----------------

__global__ void deg_k(const int* __restrict__ ei, int* __restrict__ deg, int E, int n) {
    int t = blockIdx.x * blockDim.x + threadIdx.x;
    if (t >= E + n) return;
    int d = (t < E) ? ei[E + t] : (t - E);
    atomicAdd(&deg[d], 1);
}

__global__ __launch_bounds__(256) void scan1_k(const int* __restrict__ deg, int* __restrict__ incl,
                                               int* __restrict__ bsum, int n) {
    __shared__ int wsum[4];
    int tid = threadIdx.x;
    int idx0 = blockIdx.x * 1024 + tid * 4;
    int v[4]; int s = 0;
#pragma unroll
    for (int j = 0; j < 4; ++j) { int id = idx0 + j; v[j] = (id < n) ? deg[id] : 0; s += v[j]; }
    int lane = tid & 63, w = tid >> 6;
    int ss = s;
#pragma unroll
    for (int off = 1; off < 64; off <<= 1) { int t2 = __shfl_up(ss, off); if (lane >= off) ss += t2; }
    if (lane == 63) wsum[w] = ss;
    __syncthreads();
    int woff = 0;
    for (int j = 0; j < w; ++j) woff += wsum[j];
    int run = woff + ss - s;   // exclusive prefix for this thread
#pragma unroll
    for (int j = 0; j < 4; ++j) { run += v[j]; int id = idx0 + j; if (id < n) incl[id] = run; }
    if (tid == 255) bsum[blockIdx.x] = woff + ss;
}

__global__ __launch_bounds__(128) void scan2_k(const int* __restrict__ bsum, int* __restrict__ boff,
                                               int* __restrict__ rowptr, int nb, int n) {
    __shared__ int ws0;
    int tid = threadIdx.x;
    int v = (tid < nb) ? bsum[tid] : 0;
    int lane = tid & 63, w = tid >> 6;
    int ss = v;
#pragma unroll
    for (int off = 1; off < 64; off <<= 1) { int t2 = __shfl_up(ss, off); if (lane >= off) ss += t2; }
    if (w == 0 && lane == 63) ws0 = ss;
    __syncthreads();
    if (w == 1) ss += ws0;
    if (tid < nb) boff[tid] = ss - v;
    if (tid == nb - 1) rowptr[n] = ss;
}

__global__ void scan3_k(const int* __restrict__ incl, const int* __restrict__ deg,
                        const int* __restrict__ boff, int* __restrict__ rowptr,
                        int* __restrict__ cursor, int n) {
    int i = blockIdx.x * blockDim.x + threadIdx.x;
    if (i >= n) return;
    int r = incl[i] - deg[i] + boff[i >> 10];
    rowptr[i] = r;
    cursor[i] = r;
}

__global__ void scatter_k(const int* __restrict__ ei, int* __restrict__ cursor,
                          int* __restrict__ col_src, int E, int n) {
    int t = blockIdx.x * blockDim.x + threadIdx.x;
    if (t >= E + n) return;
    int s, d;
    if (t < E) { s = ei[t]; d = ei[E + t]; } else { s = t - E; d = t - E; }
    int pos = atomicAdd(&cursor[d], 1);
    col_src[pos] = s;
}

// ---------------- Layer 1 GEMM: h1[n,64] = x[n,512] @ W1[512,64] ----------------

__global__ __launch_bounds__(256) void gemm1_k(const float* __restrict__ x, const float* __restrict__ W,
                                               float* __restrict__ h, int n) {
    __shared__ float As[32][132];
    __shared__ float Bs[32][64];
    int tid = threadIdx.x;
    int row0 = blockIdx.x * 128;
    int tx = tid & 15, ty = tid >> 4;
    float acc[8][4] = {};
    for (int k0 = 0; k0 < F_IN; k0 += 32) {
#pragma unroll
        for (int j = 0; j < 4; ++j) {
            int idx = tid + j * 256;
            int r = idx >> 3;
            int c4 = (idx & 7) << 2;
            int gr = row0 + r;
            float4 v = (gr < n) ? *(const float4*)&x[(size_t)gr * F_IN + k0 + c4]
                                : make_float4(0.f, 0.f, 0.f, 0.f);
            As[c4 + 0][r] = v.x; As[c4 + 1][r] = v.y; As[c4 + 2][r] = v.z; As[c4 + 3][r] = v.w;
        }
#pragma unroll
        for (int j = 0; j < 2; ++j) {
            int idx = tid + j * 256;
            int r = idx >> 4;
            int c4 = (idx & 15) << 2;
            *(float4*)&Bs[r][c4] = *(const float4*)&W[(size_t)(k0 + r) * HOUT + c4];
        }
        __syncthreads();
#pragma unroll
        for (int kk = 0; kk < 32; ++kk) {
            float4 a0 = *(const float4*)&As[kk][ty * 8];
            float4 a1 = *(const float4*)&As[kk][ty * 8 + 4];
            float4 bv = *(const float4*)&Bs[kk][tx * 4];
            float a[8] = {a0.x, a0.y, a0.z, a0.w, a1.x, a1.y, a1.z, a1.w};
            float b[4] = {bv.x, bv.y, bv.z, bv.w};
#pragma unroll
            for (int r = 0; r < 8; ++r)
#pragma unroll
                for (int c = 0; c < 4; ++c) acc[r][c] += a[r] * b[c];
        }
        __syncthreads();
    }
#pragma unroll
    for (int r = 0; r < 8; ++r) {
        int gr = row0 + ty * 8 + r;
        if (gr < n)
            *(float4*)&h[(size_t)gr * HOUT + tx * 4] =
                make_float4(acc[r][0], acc[r][1], acc[r][2], acc[r][3]);
    }
}

// ---------------- attention dot products layer 1 ----------------

__global__ void att1_k(const float* __restrict__ h1, const float* __restrict__ asw,
                       const float* __restrict__ adw, float* __restrict__ as1,
                       float* __restrict__ ad1, int n) {
    int t = blockIdx.x * blockDim.x + threadIdx.x;
    if (t >= n * HEADS) return;
    int hd = t & 7;
    const float* hp = h1 + (size_t)(t >> 3) * HOUT + hd * C1;
    float4 h0 = *(const float4*)hp, h1v = *(const float4*)(hp + 4);
    float4 a0 = *(const float4*)(asw + hd * C1), a1 = *(const float4*)(asw + hd * C1 + 4);
    float4 d0 = *(const float4*)(adw + hd * C1), d1 = *(const float4*)(adw + hd * C1 + 4);
    as1[t] = h0.x*a0.x + h0.y*a0.y + h0.z*a0.z + h0.w*a0.w
           + h1v.x*a1.x + h1v.y*a1.y + h1v.z*a1.z + h1v.w*a1.w;
    ad1[t] = h0.x*d0.x + h0.y*d0.y + h0.z*d0.z + h0.w*d0.w
           + h1v.x*d1.x + h1v.y*d1.y + h1v.z*d1.z + h1v.w*d1.w;
}

// ---------------- layer-1 aggregation: wave per node, lane-parallel edges ----------------

__global__ __launch_bounds__(256) void l1agg_k(const float* __restrict__ h1, const float* __restrict__ as1,
                                               const float* __restrict__ ad1, const float* __restrict__ b1,
                                               const int* __restrict__ rowptr, const int* __restrict__ col,
                                               float* __restrict__ hact, int n) {
    __shared__ float ws_all[4][8 * 68];   // [wave][h*68 + slot], padded: conflict-free r/w
    __shared__ int   ss_all[4][64];
    int wid = threadIdx.x >> 6, lane = threadIdx.x & 63;
    int node = blockIdx.x * 4 + wid;
    if (node >= n) return;
    int st = rowptr[node], en = rowptr[node + 1];
    int deg = en - st;
    float o;
    if (deg <= 64) {
        float* ws = ws_all[wid];
        int*   ss = ss_all[wid];
        bool v = lane < deg;
        int s = 0;
        float4 a0 = make_float4(0.f, 0.f, 0.f, 0.f), a1 = a0;
        if (v) {
            s = col[st + lane];
            a0 = *(const float4*)&as1[s * 8];
            a1 = *(const float4*)&as1[s * 8 + 4];
        }
        ss[lane] = s;
        float4 d0 = *(const float4*)&ad1[node * 8];
        float4 d1 = *(const float4*)&ad1[node * 8 + 4];
        float ea[8] = {a0.x + d0.x, a0.y + d0.y, a0.z + d0.z, a0.w + d0.w,
                       a1.x + d1.x, a1.y + d1.y, a1.z + d1.z, a1.w + d1.w};
#pragma unroll
        for (int h = 0; h < 8; ++h) {
            float ee = v ? (ea[h] >= 0.f ? ea[h] : NEG * ea[h]) : -1e30f;
            float m = ee;
#pragma unroll
            for (int off = 1; off < 64; off <<= 1) m = fmaxf(m, __shfl_xor(m, off));
            float p = __expf(ee - m);          // invalid lanes -> 0
            float d = p;
#pragma unroll
            for (int off = 1; off < 64; off <<= 1) d += __shfl_xor(d, off);
            ws[h * 68 + lane] = p / (d + 1e-16f);
        }
        __asm__ volatile("s_waitcnt lgkmcnt(0)" ::: "memory");
        __builtin_amdgcn_sched_barrier(0);
        int chd = lane >> 3;
        float acc = 0.f;
        for (int g = 0; g < 16; ++g) {
            if (g * 4 >= deg) break;
#pragma unroll
            for (int jj = 0; jj < 4; ++jj) {
                int j = g * 4 + jj;
                if (j < deg)
                    acc += ws[chd * 68 + j] * h1[(size_t)ss[j] * HOUT + lane];
            }
        }
        o = acc + b1[lane];
    } else {
        // rare fallback: serial online softmax (deg > 64)
        int hd = lane >> 3;
        float ad = ad1[node * HEADS + hd];
        float m = -1e30f, den = 0.f, acc = 0.f;
        for (int e = st; e < en; ++e) {
            int s = col[e];
            float e0 = as1[s * HEADS + hd] + ad;
            float ee = e0 >= 0.f ? e0 : NEG * e0;
            float hv = h1[(size_t)s * HOUT + lane];
            float mn = fmaxf(m, ee);
            float sc = __expf(m - mn), p = __expf(ee - mn);
            den = den * sc + p;
            acc = acc * sc + p * hv;
            m = mn;
        }
        o = acc / (den + 1e-16f) + b1[lane];
    }
    hact[(size_t)node * HOUT + lane] = o > 0.f ? o : expm1f(o);   // ELU
}

// ---------------- layer-2 GEMM (64->40) + attention dots ----------------

__global__ __launch_bounds__(256) void g2_k(const float* __restrict__ hact, const float* __restrict__ W2,
                                            const float* __restrict__ asw, const float* __restrict__ adw,
                                            float* __restrict__ h2, float* __restrict__ as2,
                                            float* __restrict__ ad2, int n) {
    __shared__ float W2s[HOUT * NCLS];
    for (int t = threadIdx.x; t < HOUT * NCLS; t += 256) W2s[t] = W2[t];
    __syncthreads();
    int lane = threadIdx.x & 63;
    int node = blockIdx.x * 4 + (threadIdx.x >> 6);
    if (node >= n) return;
    float hreg = hact[(size_t)node * HOUT + lane];
    int cc = lane < NCLS ? lane : 0;
    float o = 0.f;
#pragma unroll
    for (int k = 0; k < HOUT; ++k) {
        float hk = __shfl(hreg, k);
        o += hk * W2s[k * NCLS + cc];
    }
    float av = lane < NCLS ? o * asw[lane] : 0.f;
    float dv = lane < NCLS ? o * adw[lane] : 0.f;
#pragma unroll
    for (int off = 32; off > 0; off >>= 1) {
        av += __shfl_xor(av, off);
        dv += __shfl_xor(dv, off);
    }
    if (lane < NCLS) h2[(size_t)node * NCLS + lane] = o;
    if (lane == 0) { as2[node] = av; ad2[node] = dv; }
}

// ---------------- layer-2 aggregation + log_softmax ----------------

__global__ __launch_bounds__(256) void l2agg_k(const float* __restrict__ h2, const float* __restrict__ as2,
                                               const float* __restrict__ ad2, const float* __restrict__ b2,
                                               const int* __restrict__ rowptr, const int* __restrict__ col,
                                               float* __restrict__ out, int n) {
    __shared__ float ws_all[4][64];
    __shared__ int   ss_all[4][64];
    int wid = threadIdx.x >> 6, lane = threadIdx.x & 63;
    int node = blockIdx.x * 4 + wid;
    if (node >= n) return;
    bool act = lane < NCLS;
    int st = rowptr[node], en = rowptr[node + 1];
    int deg = en - st;
    float z;
    if (deg <= 64) {
        float* ws = ws_all[wid];
        int*   ss = ss_all[wid];
        bool v = lane < deg;
        int s = 0; float av = 0.f;
        if (v) {
            s = col[st + lane];
            av = as2[s];
        }
        ss[lane] = s;
        float ad = ad2[node];
        float e0 = av + ad;
        float ee = v ? (e0 >= 0.f ? e0 : NEG * e0) : -1e30f;
        float m = ee;
#pragma unroll
        for (int off = 1; off < 64; off <<= 1) m = fmaxf(m, __shfl_xor(m, off));
        float p = __expf(ee - m);
        float d = p;
#pragma unroll
        for (int off = 1; off < 64; off <<= 1) d += __shfl_xor(d, off);
        ws[lane] = p / (d + 1e-16f);
        __asm__ volatile("s_waitcnt lgkmcnt(0)" ::: "memory");
        __builtin_amdgcn_sched_barrier(0);
        float acc = 0.f;
        for (int g = 0; g < 8; ++g) {
            if (g * 8 >= deg) break;
#pragma unroll
            for (int jj = 0; jj < 8; ++jj) {
                int j = g * 8 + jj;
                if (j < deg && act)
                    acc += ws[j] * h2[(size_t)ss[j] * NCLS + lane];
            }
        }
        z = act ? acc + b2[lane] : -1e30f;
    } else {
        // rare fallback: serial online softmax (deg > 64)
        float ad = ad2[node];
        float m = -1e30f, den = 0.f, acc = 0.f;
        for (int e = st; e < en; ++e) {
            int s = col[e];
            float e0 = as2[s] + ad;
            float ee = e0 >= 0.f ? e0 : NEG * e0;
            float hv = act ? h2[(size_t)s * NCLS + lane] : 0.f;
            float mn = fmaxf(m, ee);
            float sc = __expf(m - mn), p = __expf(ee - mn);
            den = den * sc + p;
            acc = acc * sc + p * hv;
            m = mn;
        }
        z = act ? (acc / (den + 1e-16f) + b2[lane]) : -1e30f;
    }
    float zm = z;
#pragma unroll
    for (int off = 32; off > 0; off >>= 1) zm = fmaxf(zm, __shfl_xor(zm, off));
    float ex = act ? __expf(z - zm) : 0.f;
    float ss2 = ex;
#pragma unroll
    for (int off = 32; off > 0; off >>= 1) ss2 += __shfl_xor(ss2, off);
    if (act) out[(size_t)node * NCLS + lane] = z - zm - logf(ss2);
}

// ---------------- host ----------------

extern "C" void kernel_launch(void* const* d_in, const int* in_sizes, int n_in,
                              void* d_out, int out_size, void* d_ws, size_t ws_size,
                              hipStream_t stream) {
    const float* x    = (const float*)d_in[0];
    const int*   ei   = (const int*)d_in[1];
    const float* W1   = (const float*)d_in[2];
    const float* asw1 = (const float*)d_in[3];
    const float* adw1 = (const float*)d_in[4];
    const float* b1   = (const float*)d_in[5];
    const float* W2   = (const float*)d_in[6];
    const float* asw2 = (const float*)d_in[7];
    const float* adw2 = (const float*)d_in[8];
    const float* b2   = (const float*)d_in[9];
    float* out = (float*)d_out;

    const int n = in_sizes[0] / F_IN;          // 100000
    const int E = in_sizes[1] / 2;             // 1600000
    const int Etot = E + n;

    char* ws = (char*)d_ws;
    size_t off = 0;
    auto alloc = [&](size_t bytes) -> void* {
        void* p = ws + off;
        off = (off + bytes + 255) & ~(size_t)255;
        return p;
    };
    int*   deg    = (int*)alloc((size_t)n * 4);
    int*   cursor = (int*)alloc((size_t)n * 4);
    int*   rowptr = (int*)alloc((size_t)(n + 1) * 4);
    int*   incl   = (int*)alloc((size_t)n * 4);
    int*   bsum   = (int*)alloc(512);
    int*   boff   = (int*)alloc(512);
    int*   col    = (int*)alloc((size_t)Etot * 4);
    float* h1     = (float*)alloc((size_t)n * HOUT * 4);   // reused for h2/as2/ad2 after l1agg
    float* as1    = (float*)alloc((size_t)n * HEADS * 4);
    float* ad1    = (float*)alloc((size_t)n * HEADS * 4);
    float* hact   = (float*)alloc((size_t)n * HOUT * 4);
    float* h2  = h1;
    float* as2 = h1 + (size_t)n * NCLS;
    float* ad2 = h1 + (size_t)n * (NCLS + 1);

    const int nb = (n + 1023) / 1024;

    hipMemsetAsync(deg, 0, (size_t)n * 4, stream);
    deg_k<<<(Etot + 255) / 256, 256, 0, stream>>>(ei, deg, E, n);
    scan1_k<<<nb, 256, 0, stream>>>(deg, incl, bsum, n);
    scan2_k<<<1, 128, 0, stream>>>(bsum, boff, rowptr, nb, n);
    scan3_k<<<(n + 255) / 256, 256, 0, stream>>>(incl, deg, boff, rowptr, cursor, n);
    scatter_k<<<(Etot + 255) / 256, 256, 0, stream>>>(ei, cursor, col, E, n);

    gemm1_k<<<(n + 127) / 128, 256, 0, stream>>>(x, W1, h1, n);
    att1_k<<<(n * HEADS + 255) / 256, 256, 0, stream>>>(h1, asw1, adw1, as1, ad1, n);
    l1agg_k<<<(n + 3) / 4, 256, 0, stream>>>(h1, as1, ad1, b1, rowptr, col, hact, n);
    g2_k<<<(n + 3) / 4, 256, 0, stream>>>(hact, W2, asw2, adw2, h2, as2, ad2, n);
    l2agg_k<<<(n + 3) / 4, 256, 0, stream>>>(h2, as2, ad2, b2, rowptr, col, out, n);
}

// Round 3
// 695.091 us; speedup vs baseline: 1.1563x; 1.0482x over previous
//
#include <hip/hip_runtime.h>
#include <hip/hip_bf16.h>
#include <math.h>

#define F_IN 512
#define HOUT 64      // HEADS*C1
#define HEADS 8
#define C1 8
#define NCLS 40
#define NEG 0.2f

// ---------------- CSR build ----------------

__global__ void deg_k(const int* __restrict__ ei, int* __restrict__ deg, int E, int n) {
    int t = blockIdx.x * blockDim.x + threadIdx.x;
    if (t >= E + n) return;
    int d = (t < E) ? ei[E + t] : (t - E);
    atomicAdd(&deg[d], 1);
}

__global__ __launch_bounds__(256) void scan1_k(const int* __restrict__ deg, int* __restrict__ incl,
                                               int* __restrict__ bsum, int n) {
    __shared__ int wsum[4];
    int tid = threadIdx.x;
    int idx0 = blockIdx.x * 1024 + tid * 4;
    int v[4]; int s = 0;
#pragma unroll
    for (int j = 0; j < 4; ++j) { int id = idx0 + j; v[j] = (id < n) ? deg[id] : 0; s += v[j]; }
    int lane = tid & 63, w = tid >> 6;
    int ss = s;
#pragma unroll
    for (int off = 1; off < 64; off <<= 1) { int t2 = __shfl_up(ss, off); if (lane >= off) ss += t2; }
    if (lane == 63) wsum[w] = ss;
    __syncthreads();
    int woff = 0;
    for (int j = 0; j < w; ++j) woff += wsum[j];
    int run = woff + ss - s;   // exclusive prefix for this thread
#pragma unroll
    for (int j = 0; j < 4; ++j) { run += v[j]; int id = idx0 + j; if (id < n) incl[id] = run; }
    if (tid == 255) bsum[blockIdx.x] = woff + ss;
}

__global__ __launch_bounds__(128) void scan2_k(const int* __restrict__ bsum, int* __restrict__ boff,
                                               int* __restrict__ rowptr, int nb, int n) {
    __shared__ int ws0;
    int tid = threadIdx.x;
    int v = (tid < nb) ? bsum[tid] : 0;
    int lane = tid & 63, w = tid >> 6;
    int ss = v;
#pragma unroll
    for (int off = 1; off < 64; off <<= 1) { int t2 = __shfl_up(ss, off); if (lane >= off) ss += t2; }
    if (w == 0 && lane == 63) ws0 = ss;
    __syncthreads();
    if (w == 1) ss += ws0;
    if (tid < nb) boff[tid] = ss - v;
    if (tid == nb - 1) rowptr[n] = ss;
}

__global__ void scan3_k(const int* __restrict__ incl, const int* __restrict__ deg,
                        const int* __restrict__ boff, int* __restrict__ rowptr,
                        int* __restrict__ cursor, int n) {
    int i = blockIdx.x * blockDim.x + threadIdx.x;
    if (i >= n) return;
    int r = incl[i] - deg[i] + boff[i >> 10];
    rowptr[i] = r;
    cursor[i] = r;
}

__global__ void scatter_k(const int* __restrict__ ei, int* __restrict__ cursor,
                          int* __restrict__ col_src, int E, int n) {
    int t = blockIdx.x * blockDim.x + threadIdx.x;
    if (t >= E + n) return;
    int s, d;
    if (t < E) { s = ei[t]; d = ei[E + t]; } else { s = t - E; d = t - E; }
    int pos = atomicAdd(&cursor[d], 1);
    col_src[pos] = s;
}

// ---------------- Layer 1 GEMM: h1[n,64] = x[n,512] @ W1[512,64] ----------------

__global__ __launch_bounds__(256) void gemm1_k(const float* __restrict__ x, const float* __restrict__ W,
                                               float* __restrict__ h, int n) {
    __shared__ float As[32][132];
    __shared__ float Bs[32][64];
    int tid = threadIdx.x;
    int row0 = blockIdx.x * 128;
    int tx = tid & 15, ty = tid >> 4;
    float acc[8][4] = {};
    for (int k0 = 0; k0 < F_IN; k0 += 32) {
#pragma unroll
        for (int j = 0; j < 4; ++j) {
            int idx = tid + j * 256;
            int r = idx >> 3;
            int c4 = (idx & 7) << 2;
            int gr = row0 + r;
            float4 v = (gr < n) ? *(const float4*)&x[(size_t)gr * F_IN + k0 + c4]
                                : make_float4(0.f, 0.f, 0.f, 0.f);
            As[c4 + 0][r] = v.x; As[c4 + 1][r] = v.y; As[c4 + 2][r] = v.z; As[c4 + 3][r] = v.w;
        }
#pragma unroll
        for (int j = 0; j < 2; ++j) {
            int idx = tid + j * 256;
            int r = idx >> 4;
            int c4 = (idx & 15) << 2;
            *(float4*)&Bs[r][c4] = *(const float4*)&W[(size_t)(k0 + r) * HOUT + c4];
        }
        __syncthreads();
#pragma unroll
        for (int kk = 0; kk < 32; ++kk) {
            float4 a0 = *(const float4*)&As[kk][ty * 8];
            float4 a1 = *(const float4*)&As[kk][ty * 8 + 4];
            float4 bv = *(const float4*)&Bs[kk][tx * 4];
            float a[8] = {a0.x, a0.y, a0.z, a0.w, a1.x, a1.y, a1.z, a1.w};
            float b[4] = {bv.x, bv.y, bv.z, bv.w};
#pragma unroll
            for (int r = 0; r < 8; ++r)
#pragma unroll
                for (int c = 0; c < 4; ++c) acc[r][c] += a[r] * b[c];
        }
        __syncthreads();
    }
#pragma unroll
    for (int r = 0; r < 8; ++r) {
        int gr = row0 + ty * 8 + r;
        if (gr < n)
            *(float4*)&h[(size_t)gr * HOUT + tx * 4] =
                make_float4(acc[r][0], acc[r][1], acc[r][2], acc[r][3]);
    }
}

// ---------------- attention dot products layer 1 ----------------

__global__ void att1_k(const float* __restrict__ h1, const float* __restrict__ asw,
                       const float* __restrict__ adw, float* __restrict__ as1,
                       float* __restrict__ ad1, int n) {
    int t = blockIdx.x * blockDim.x + threadIdx.x;
    if (t >= n * HEADS) return;
    int hd = t & 7;
    const float* hp = h1 + (size_t)(t >> 3) * HOUT + hd * C1;
    float4 h0 = *(const float4*)hp, h1v = *(const float4*)(hp + 4);
    float4 a0 = *(const float4*)(asw + hd * C1), a1 = *(const float4*)(asw + hd * C1 + 4);
    float4 d0 = *(const float4*)(adw + hd * C1), d1 = *(const float4*)(adw + hd * C1 + 4);
    as1[t] = h0.x*a0.x + h0.y*a0.y + h0.z*a0.z + h0.w*a0.w
           + h1v.x*a1.x + h1v.y*a1.y + h1v.z*a1.z + h1v.w*a1.w;
    ad1[t] = h0.x*d0.x + h0.y*d0.y + h0.z*d0.z + h0.w*d0.w
           + h1v.x*d1.x + h1v.y*d1.y + h1v.z*d1.z + h1v.w*d1.w;
}

// ---------------- layer-1 aggregation: wave per node, lane-parallel edges ----------------
// Softmax via LDS transpose: 6 shuffles/node instead of 96 (DS-pipe was the bottleneck).

__global__ __launch_bounds__(256) void l1agg_k(const float* __restrict__ h1, const float* __restrict__ as1,
                                               const float* __restrict__ ad1, const float* __restrict__ b1,
                                               const int* __restrict__ rowptr, const int* __restrict__ col,
                                               float* __restrict__ hact, int n) {
    __shared__ float ws_all[4][8 * 68];   // [wave][h*68 + slot]
    __shared__ int   ss_all[4][64];
    int wid = threadIdx.x >> 6, lane = threadIdx.x & 63;
    int node = blockIdx.x * 4 + wid;
    if (node >= n) return;
    int st = rowptr[node], en = rowptr[node + 1];
    int deg = en - st;
    float o;
    if (deg <= 64) {
        float* ws = ws_all[wid];
        int*   ss = ss_all[wid];
        bool v = lane < deg;
        int s = 0;
        float4 a0 = make_float4(0.f, 0.f, 0.f, 0.f), a1 = a0;
        if (v) {
            s = col[st + lane];
            a0 = *(const float4*)&as1[s * 8];
            a1 = *(const float4*)&as1[s * 8 + 4];
        }
        ss[lane] = s;
        float4 d0 = *(const float4*)&ad1[node * 8];
        float4 d1 = *(const float4*)&ad1[node * 8 + 4];
        float ea[8] = {a0.x + d0.x, a0.y + d0.y, a0.z + d0.z, a0.w + d0.w,
                       a1.x + d1.x, a1.y + d1.y, a1.z + d1.z, a1.w + d1.w};
        // phase 1: store ee[h][slot] (leaky-relu'd; invalid slots = -1e30)
#pragma unroll
        for (int h = 0; h < 8; ++h) {
            float e0 = ea[h];
            float ee = v ? (e0 >= 0.f ? e0 : NEG * e0) : -1e30f;
            ws[h * 68 + lane] = ee;
        }
        __asm__ volatile("s_waitcnt lgkmcnt(0)" ::: "memory");
        __builtin_amdgcn_sched_barrier(0);
        // phase 2: lane = (head h, sublane t); each lane owns slots {t, t+8, ..., t+56} of head h
        {
            int h = lane >> 3, t = lane & 7;
            float e[8];
#pragma unroll
            for (int u = 0; u < 8; ++u) e[u] = ws[h * 68 + t + 8 * u];
            float mx = e[0];
#pragma unroll
            for (int u = 1; u < 8; ++u) mx = fmaxf(mx, e[u]);
            mx = fmaxf(mx, __shfl_xor(mx, 1));
            mx = fmaxf(mx, __shfl_xor(mx, 2));
            mx = fmaxf(mx, __shfl_xor(mx, 4));     // head max in all 8 lanes of group
            float p[8], sm = 0.f;
#pragma unroll
            for (int u = 0; u < 8; ++u) { p[u] = __expf(e[u] - mx); sm += p[u]; }
            sm += __shfl_xor(sm, 1);
            sm += __shfl_xor(sm, 2);
            sm += __shfl_xor(sm, 4);               // head denominator
            float inv = 1.f / (sm + 1e-16f);
#pragma unroll
            for (int u = 0; u < 8; ++u) ws[h * 68 + t + 8 * u] = p[u] * inv;
        }
        __asm__ volatile("s_waitcnt lgkmcnt(0)" ::: "memory");
        __builtin_amdgcn_sched_barrier(0);
        // phase 3: lane = output channel; accumulate weighted h1 rows
        int chd = lane >> 3;
        float acc = 0.f;
        for (int g = 0; g < 16; ++g) {
            if (g * 4 >= deg) break;
#pragma unroll
            for (int jj = 0; jj < 4; ++jj) {
                int j = g * 4 + jj;
                if (j < deg)
                    acc += ws[chd * 68 + j] * h1[(size_t)ss[j] * HOUT + lane];
            }
        }
        o = acc + b1[lane];
    } else {
        // rare fallback: serial online softmax (deg > 64)
        int hd = lane >> 3;
        float ad = ad1[node * HEADS + hd];
        float m = -1e30f, den = 0.f, acc = 0.f;
        for (int e = st; e < en; ++e) {
            int s = col[e];
            float e0 = as1[s * HEADS + hd] + ad;
            float ee = e0 >= 0.f ? e0 : NEG * e0;
            float hv = h1[(size_t)s * HOUT + lane];
            float mn = fmaxf(m, ee);
            float sc = __expf(m - mn), p = __expf(ee - mn);
            den = den * sc + p;
            acc = acc * sc + p * hv;
            m = mn;
        }
        o = acc / (den + 1e-16f) + b1[lane];
    }
    hact[(size_t)node * HOUT + lane] = o > 0.f ? o : expm1f(o);   // ELU
}

// ---------------- layer-2 GEMM (64->40) + attention dots ----------------

__global__ __launch_bounds__(256) void g2_k(const float* __restrict__ hact, const float* __restrict__ W2,
                                            const float* __restrict__ asw, const float* __restrict__ adw,
                                            float* __restrict__ h2, float* __restrict__ as2,
                                            float* __restrict__ ad2, int n) {
    __shared__ float W2s[HOUT * NCLS];
    for (int t = threadIdx.x; t < HOUT * NCLS; t += 256) W2s[t] = W2[t];
    __syncthreads();
    int lane = threadIdx.x & 63;
    int node = blockIdx.x * 4 + (threadIdx.x >> 6);
    if (node >= n) return;
    float hreg = hact[(size_t)node * HOUT + lane];
    int cc = lane < NCLS ? lane : 0;
    float o = 0.f;
#pragma unroll
    for (int k = 0; k < HOUT; ++k) {
        float hk = __shfl(hreg, k);
        o += hk * W2s[k * NCLS + cc];
    }
    float av = lane < NCLS ? o * asw[lane] : 0.f;
    float dv = lane < NCLS ? o * adw[lane] : 0.f;
#pragma unroll
    for (int off = 32; off > 0; off >>= 1) {
        av += __shfl_xor(av, off);
        dv += __shfl_xor(dv, off);
    }
    if (lane < NCLS) h2[(size_t)node * NCLS + lane] = o;
    if (lane == 0) { as2[node] = av; ad2[node] = dv; }
}

// ---------------- layer-2 aggregation + log_softmax ----------------

__global__ __launch_bounds__(256) void l2agg_k(const float* __restrict__ h2, const float* __restrict__ as2,
                                               const float* __restrict__ ad2, const float* __restrict__ b2,
                                               const int* __restrict__ rowptr, const int* __restrict__ col,
                                               float* __restrict__ out, int n) {
    __shared__ float ws_all[4][64];
    __shared__ int   ss_all[4][64];
    int wid = threadIdx.x >> 6, lane = threadIdx.x & 63;
    int node = blockIdx.x * 4 + wid;
    if (node >= n) return;
    bool act = lane < NCLS;
    int st = rowptr[node], en = rowptr[node + 1];
    int deg = en - st;
    float z;
    if (deg <= 64) {
        float* ws = ws_all[wid];
        int*   ss = ss_all[wid];
        bool v = lane < deg;
        int s = 0; float av = 0.f;
        if (v) {
            s = col[st + lane];
            av = as2[s];
        }
        ss[lane] = s;
        float ad = ad2[node];
        float e0 = av + ad;
        float ee = v ? (e0 >= 0.f ? e0 : NEG * e0) : -1e30f;
        float m = ee;
#pragma unroll
        for (int off = 1; off < 64; off <<= 1) m = fmaxf(m, __shfl_xor(m, off));
        float p = __expf(ee - m);
        float d = p;
#pragma unroll
        for (int off = 1; off < 64; off <<= 1) d += __shfl_xor(d, off);
        ws[lane] = p / (d + 1e-16f);
        __asm__ volatile("s_waitcnt lgkmcnt(0)" ::: "memory");
        __builtin_amdgcn_sched_barrier(0);
        float acc = 0.f;
        for (int g = 0; g < 8; ++g) {
            if (g * 8 >= deg) break;
#pragma unroll
            for (int jj = 0; jj < 8; ++jj) {
                int j = g * 8 + jj;
                if (j < deg && act)
                    acc += ws[j] * h2[(size_t)ss[j] * NCLS + lane];
            }
        }
        z = act ? acc + b2[lane] : -1e30f;
    } else {
        // rare fallback: serial online softmax (deg > 64)
        float ad = ad2[node];
        float m = -1e30f, den = 0.f, acc = 0.f;
        for (int e = st; e < en; ++e) {
            int s = col[e];
            float e0 = as2[s] + ad;
            float ee = e0 >= 0.f ? e0 : NEG * e0;
            float hv = act ? h2[(size_t)s * NCLS + lane] : 0.f;
            float mn = fmaxf(m, ee);
            float sc = __expf(m - mn), p = __expf(ee - mn);
            den = den * sc + p;
            acc = acc * sc + p * hv;
            m = mn;
        }
        z = act ? (acc / (den + 1e-16f) + b2[lane]) : -1e30f;
    }
    float zm = z;
#pragma unroll
    for (int off = 32; off > 0; off >>= 1) zm = fmaxf(zm, __shfl_xor(zm, off));
    float ex = act ? __expf(z - zm) : 0.f;
    float ss2 = ex;
#pragma unroll
    for (int off = 32; off > 0; off >>= 1) ss2 += __shfl_xor(ss2, off);
    if (act) out[(size_t)node * NCLS + lane] = z - zm - logf(ss2);
}

// ---------------- host ----------------

extern "C" void kernel_launch(void* const* d_in, const int* in_sizes, int n_in,
                              void* d_out, int out_size, void* d_ws, size_t ws_size,
                              hipStream_t stream) {
    const float* x    = (const float*)d_in[0];
    const int*   ei   = (const int*)d_in[1];
    const float* W1   = (const float*)d_in[2];
    const float* asw1 = (const float*)d_in[3];
    const float* adw1 = (const float*)d_in[4];
    const float* b1   = (const float*)d_in[5];
    const float* W2   = (const float*)d_in[6];
    const float* asw2 = (const float*)d_in[7];
    const float* adw2 = (const float*)d_in[8];
    const float* b2   = (const float*)d_in[9];
    float* out = (float*)d_out;

    const int n = in_sizes[0] / F_IN;          // 100000
    const int E = in_sizes[1] / 2;             // 1600000
    const int Etot = E + n;

    char* ws = (char*)d_ws;
    size_t off = 0;
    auto alloc = [&](size_t bytes) -> void* {
        void* p = ws + off;
        off = (off + bytes + 255) & ~(size_t)255;
        return p;
    };
    int*   deg    = (int*)alloc((size_t)n * 4);
    int*   cursor = (int*)alloc((size_t)n * 4);
    int*   rowptr = (int*)alloc((size_t)(n + 1) * 4);
    int*   incl   = (int*)alloc((size_t)n * 4);
    int*   bsum   = (int*)alloc(512);
    int*   boff   = (int*)alloc(512);
    int*   col    = (int*)alloc((size_t)Etot * 4);
    float* h1     = (float*)alloc((size_t)n * HOUT * 4);   // reused for h2/as2/ad2 after l1agg
    float* as1    = (float*)alloc((size_t)n * HEADS * 4);
    float* ad1    = (float*)alloc((size_t)n * HEADS * 4);
    float* hact   = (float*)alloc((size_t)n * HOUT * 4);
    float* h2  = h1;
    float* as2 = h1 + (size_t)n * NCLS;
    float* ad2 = h1 + (size_t)n * (NCLS + 1);

    const int nb = (n + 1023) / 1024;

    hipMemsetAsync(deg, 0, (size_t)n * 4, stream);
    deg_k<<<(Etot + 255) / 256, 256, 0, stream>>>(ei, deg, E, n);
    scan1_k<<<nb, 256, 0, stream>>>(deg, incl, bsum, n);
    scan2_k<<<1, 128, 0, stream>>>(bsum, boff, rowptr, nb, n);
    scan3_k<<<(n + 255) / 256, 256, 0, stream>>>(incl, deg, boff, rowptr, cursor, n);
    scatter_k<<<(Etot + 255) / 256, 256, 0, stream>>>(ei, cursor, col, E, n);

    gemm1_k<<<(n + 127) / 128, 256, 0, stream>>>(x, W1, h1, n);
    att1_k<<<(n * HEADS + 255) / 256, 256, 0, stream>>>(h1, asw1, adw1, as1, ad1, n);
    l1agg_k<<<(n + 3) / 4, 256, 0, stream>>>(h1, as1, ad1, b1, rowptr, col, hact, n);
    g2_k<<<(n + 3) / 4, 256, 0, stream>>>(hact, W2, asw2, adw2, h2, as2, ad2, n);
    l2agg_k<<<(n + 3) / 4, 256, 0, stream>>>(h2, as2, ad2, b2, rowptr, col, out, n);
}

// Round 4
// 534.414 us; speedup vs baseline: 1.5039x; 1.3007x over previous
//
#include <hip/hip_runtime.h>
#include <hip/hip_bf16.h>
#include <math.h>

#define F_IN 512
#define HOUT 64      // HEADS*C1
#define HEADS 8
#define C1 8
#define NCLS 40
#define NEG 0.2f

#define DPB 256            // dsts per bucket
#define CAP 8064           // staging capacity per bucket (mean load ~4350, 50+ sigma margin)
#define EPT 32             // edges per thread in passA

// ---------------- CSR build: bucketed counting sort ----------------

__global__ __launch_bounds__(512) void init_k(int* __restrict__ gcur, int nbuck) {
    int b = blockIdx.x * 512 + threadIdx.x;
    if (b < nbuck) gcur[b] = b * CAP;
}

// passA: scatter (src,dst) pairs into bucket-major staging, block-chunked
__global__ __launch_bounds__(256) void passA_k(const int* __restrict__ ei, int* __restrict__ gcur,
                                               int2* __restrict__ bkt, int E, int Etot, int nbuck) {
    __shared__ int hist[512];
    __shared__ int lbase[512];
    int t = threadIdx.x;
    int base_e = blockIdx.x * (256 * EPT);
    for (int j = t; j < nbuck; j += 256) hist[j] = 0;
    __syncthreads();
    int s[EPT], d[EPT];
#pragma unroll
    for (int j = 0; j < EPT; ++j) {
        int idx = base_e + j * 256 + t;
        if (idx < Etot) {
            if (idx < E) { s[j] = ei[idx]; d[j] = ei[E + idx]; }
            else         { s[j] = idx - E; d[j] = idx - E; }
            atomicAdd(&hist[d[j] >> 8], 1);
        } else { s[j] = -1; d[j] = 0; }
    }
    __syncthreads();
    for (int j = t; j < nbuck; j += 256) {
        int c = hist[j];
        lbase[j] = c ? atomicAdd(&gcur[j], c) : 0;
    }
    __syncthreads();
    for (int j = t; j < nbuck; j += 256) hist[j] = 0;
    __syncthreads();
#pragma unroll
    for (int j = 0; j < EPT; ++j) {
        if (s[j] >= 0) {
            int b = d[j] >> 8;
            int slot = atomicAdd(&hist[b], 1);
            bkt[lbase[b] + slot] = make_int2(s[j], d[j]);
        }
    }
}

// bscan: exclusive scan of bucket counts -> per-bucket col base
__global__ __launch_bounds__(512) void bscan_k(const int* __restrict__ gcur, int* __restrict__ bbase,
                                               int* __restrict__ rowptr, int nbuck, int n, int Etot) {
    __shared__ int wsum[8];
    int t = threadIdx.x;
    int v = (t < nbuck) ? gcur[t] - t * CAP : 0;
    int lane = t & 63, w = t >> 6;
    int ss = v;
#pragma unroll
    for (int off = 1; off < 64; off <<= 1) { int t2 = __shfl_up(ss, off); if (lane >= off) ss += t2; }
    if (lane == 63) wsum[w] = ss;
    __syncthreads();
    int woff = 0;
    for (int j = 0; j < w; ++j) woff += wsum[j];
    if (t < nbuck) bbase[t] = woff + ss - v;
    if (t == 0) rowptr[n] = Etot;
}

// passB: one block per bucket -> rowptr + dst-sorted col
__global__ __launch_bounds__(256) void passB_k(const int2* __restrict__ bkt, const int* __restrict__ gcur,
                                               const int* __restrict__ bbase, int* __restrict__ rowptr,
                                               int* __restrict__ col, int n) {
    __shared__ int hist[DPB];
    __shared__ int lcur[DPB];
    __shared__ int wsum[4];
    int b = blockIdx.x;
    int t = threadIdx.x;
    int cnt = gcur[b] - b * CAP;
    int base = bbase[b];
    int d0 = b * DPB;
    int ndst = min(DPB, n - d0);
    const int2* src = bkt + (size_t)b * CAP;
    hist[t] = 0;
    __syncthreads();
    for (int e = t; e < cnt; e += 256) {
        int2 v = src[e];
        atomicAdd(&hist[v.y - d0], 1);
    }
    __syncthreads();
    // block exclusive scan over 256 hist entries
    int v = hist[t];
    int lane = t & 63, w = t >> 6;
    int ss = v;
#pragma unroll
    for (int off = 1; off < 64; off <<= 1) { int t2 = __shfl_up(ss, off); if (lane >= off) ss += t2; }
    if (lane == 63) wsum[w] = ss;
    __syncthreads();
    int woff = 0;
    for (int j = 0; j < w; ++j) woff += wsum[j];
    int excl = woff + ss - v;
    if (t < ndst) rowptr[d0 + t] = base + excl;
    lcur[t] = excl;
    __syncthreads();
    for (int e = t; e < cnt; e += 256) {
        int2 v2 = src[e];
        int pos = atomicAdd(&lcur[v2.y - d0], 1);
        col[base + pos] = v2.x;
    }
}

// ---------------- Layer 1 GEMM: h1[n,64] = x[n,512] @ W1[512,64] ----------------

__global__ __launch_bounds__(256) void gemm1_k(const float* __restrict__ x, const float* __restrict__ W,
                                               float* __restrict__ h, int n) {
    __shared__ float As[32][132];
    __shared__ float Bs[32][64];
    int tid = threadIdx.x;
    int row0 = blockIdx.x * 128;
    int tx = tid & 15, ty = tid >> 4;
    float acc[8][4] = {};
    for (int k0 = 0; k0 < F_IN; k0 += 32) {
#pragma unroll
        for (int j = 0; j < 4; ++j) {
            int idx = tid + j * 256;
            int r = idx >> 3;
            int c4 = (idx & 7) << 2;
            int gr = row0 + r;
            float4 v = (gr < n) ? *(const float4*)&x[(size_t)gr * F_IN + k0 + c4]
                                : make_float4(0.f, 0.f, 0.f, 0.f);
            As[c4 + 0][r] = v.x; As[c4 + 1][r] = v.y; As[c4 + 2][r] = v.z; As[c4 + 3][r] = v.w;
        }
#pragma unroll
        for (int j = 0; j < 2; ++j) {
            int idx = tid + j * 256;
            int r = idx >> 4;
            int c4 = (idx & 15) << 2;
            *(float4*)&Bs[r][c4] = *(const float4*)&W[(size_t)(k0 + r) * HOUT + c4];
        }
        __syncthreads();
#pragma unroll
        for (int kk = 0; kk < 32; ++kk) {
            float4 a0 = *(const float4*)&As[kk][ty * 8];
            float4 a1 = *(const float4*)&As[kk][ty * 8 + 4];
            float4 bv = *(const float4*)&Bs[kk][tx * 4];
            float a[8] = {a0.x, a0.y, a0.z, a0.w, a1.x, a1.y, a1.z, a1.w};
            float b[4] = {bv.x, bv.y, bv.z, bv.w};
#pragma unroll
            for (int r = 0; r < 8; ++r)
#pragma unroll
                for (int c = 0; c < 4; ++c) acc[r][c] += a[r] * b[c];
        }
        __syncthreads();
    }
#pragma unroll
    for (int r = 0; r < 8; ++r) {
        int gr = row0 + ty * 8 + r;
        if (gr < n)
            *(float4*)&h[(size_t)gr * HOUT + tx * 4] =
                make_float4(acc[r][0], acc[r][1], acc[r][2], acc[r][3]);
    }
}

// ---------------- attention dot products layer 1 ----------------

__global__ void att1_k(const float* __restrict__ h1, const float* __restrict__ asw,
                       const float* __restrict__ adw, float* __restrict__ as1,
                       float* __restrict__ ad1, int n) {
    int t = blockIdx.x * blockDim.x + threadIdx.x;
    if (t >= n * HEADS) return;
    int hd = t & 7;
    const float* hp = h1 + (size_t)(t >> 3) * HOUT + hd * C1;
    float4 h0 = *(const float4*)hp, h1v = *(const float4*)(hp + 4);
    float4 a0 = *(const float4*)(asw + hd * C1), a1 = *(const float4*)(asw + hd * C1 + 4);
    float4 d0 = *(const float4*)(adw + hd * C1), d1 = *(const float4*)(adw + hd * C1 + 4);
    as1[t] = h0.x*a0.x + h0.y*a0.y + h0.z*a0.z + h0.w*a0.w
           + h1v.x*a1.x + h1v.y*a1.y + h1v.z*a1.z + h1v.w*a1.w;
    ad1[t] = h0.x*d0.x + h0.y*d0.y + h0.z*d0.z + h0.w*d0.w
           + h1v.x*d1.x + h1v.y*d1.y + h1v.z*d1.z + h1v.w*d1.w;
}

// ---------------- layer-1 aggregation: wave per node, lane-parallel edges ----------------

__global__ __launch_bounds__(256) void l1agg_k(const float* __restrict__ h1, const float* __restrict__ as1,
                                               const float* __restrict__ ad1, const float* __restrict__ b1,
                                               const int* __restrict__ rowptr, const int* __restrict__ col,
                                               float* __restrict__ hact, int n) {
    __shared__ float ws_all[4][8 * 68];
    __shared__ int   ss_all[4][64];
    int wid = threadIdx.x >> 6, lane = threadIdx.x & 63;
    int node = blockIdx.x * 4 + wid;
    if (node >= n) return;
    int st = rowptr[node], en = rowptr[node + 1];
    int deg = en - st;
    float o;
    if (deg <= 64) {
        float* ws = ws_all[wid];
        int*   ss = ss_all[wid];
        bool v = lane < deg;
        int s = 0;
        float4 a0 = make_float4(0.f, 0.f, 0.f, 0.f), a1 = a0;
        if (v) {
            s = col[st + lane];
            a0 = *(const float4*)&as1[s * 8];
            a1 = *(const float4*)&as1[s * 8 + 4];
        }
        ss[lane] = s;
        float4 d0 = *(const float4*)&ad1[node * 8];
        float4 d1 = *(const float4*)&ad1[node * 8 + 4];
        float ea[8] = {a0.x + d0.x, a0.y + d0.y, a0.z + d0.z, a0.w + d0.w,
                       a1.x + d1.x, a1.y + d1.y, a1.z + d1.z, a1.w + d1.w};
#pragma unroll
        for (int h = 0; h < 8; ++h) {
            float e0 = ea[h];
            float ee = v ? (e0 >= 0.f ? e0 : NEG * e0) : -1e30f;
            ws[h * 68 + lane] = ee;
        }
        __asm__ volatile("s_waitcnt lgkmcnt(0)" ::: "memory");
        __builtin_amdgcn_sched_barrier(0);
        {
            int h = lane >> 3, t = lane & 7;
            float e[8];
#pragma unroll
            for (int u = 0; u < 8; ++u) e[u] = ws[h * 68 + t + 8 * u];
            float mx = e[0];
#pragma unroll
            for (int u = 1; u < 8; ++u) mx = fmaxf(mx, e[u]);
            mx = fmaxf(mx, __shfl_xor(mx, 1));
            mx = fmaxf(mx, __shfl_xor(mx, 2));
            mx = fmaxf(mx, __shfl_xor(mx, 4));
            float p[8], sm = 0.f;
#pragma unroll
            for (int u = 0; u < 8; ++u) { p[u] = __expf(e[u] - mx); sm += p[u]; }
            sm += __shfl_xor(sm, 1);
            sm += __shfl_xor(sm, 2);
            sm += __shfl_xor(sm, 4);
            float inv = 1.f / (sm + 1e-16f);
#pragma unroll
            for (int u = 0; u < 8; ++u) ws[h * 68 + t + 8 * u] = p[u] * inv;
        }
        __asm__ volatile("s_waitcnt lgkmcnt(0)" ::: "memory");
        __builtin_amdgcn_sched_barrier(0);
        int chd = lane >> 3;
        float acc = 0.f;
        for (int g = 0; g < 16; ++g) {
            if (g * 4 >= deg) break;
#pragma unroll
            for (int jj = 0; jj < 4; ++jj) {
                int j = g * 4 + jj;
                if (j < deg)
                    acc += ws[chd * 68 + j] * h1[(size_t)ss[j] * HOUT + lane];
            }
        }
        o = acc + b1[lane];
    } else {
        int hd = lane >> 3;
        float ad = ad1[node * HEADS + hd];
        float m = -1e30f, den = 0.f, acc = 0.f;
        for (int e = st; e < en; ++e) {
            int s = col[e];
            float e0 = as1[s * HEADS + hd] + ad;
            float ee = e0 >= 0.f ? e0 : NEG * e0;
            float hv = h1[(size_t)s * HOUT + lane];
            float mn = fmaxf(m, ee);
            float sc = __expf(m - mn), p = __expf(ee - mn);
            den = den * sc + p;
            acc = acc * sc + p * hv;
            m = mn;
        }
        o = acc / (den + 1e-16f) + b1[lane];
    }
    hact[(size_t)node * HOUT + lane] = o > 0.f ? o : expm1f(o);   // ELU
}

// ---------------- layer-2 GEMM (64->40) + attention dots ----------------

__global__ __launch_bounds__(256) void g2_k(const float* __restrict__ hact, const float* __restrict__ W2,
                                            const float* __restrict__ asw, const float* __restrict__ adw,
                                            float* __restrict__ h2, float* __restrict__ as2,
                                            float* __restrict__ ad2, int n) {
    __shared__ float W2s[HOUT * NCLS];
    for (int t = threadIdx.x; t < HOUT * NCLS; t += 256) W2s[t] = W2[t];
    __syncthreads();
    int lane = threadIdx.x & 63;
    int node = blockIdx.x * 4 + (threadIdx.x >> 6);
    if (node >= n) return;
    float hreg = hact[(size_t)node * HOUT + lane];
    int cc = lane < NCLS ? lane : 0;
    float o = 0.f;
#pragma unroll
    for (int k = 0; k < HOUT; ++k) {
        float hk = __shfl(hreg, k);
        o += hk * W2s[k * NCLS + cc];
    }
    float av = lane < NCLS ? o * asw[lane] : 0.f;
    float dv = lane < NCLS ? o * adw[lane] : 0.f;
#pragma unroll
    for (int off = 32; off > 0; off >>= 1) {
        av += __shfl_xor(av, off);
        dv += __shfl_xor(dv, off);
    }
    if (lane < NCLS) h2[(size_t)node * NCLS + lane] = o;
    if (lane == 0) { as2[node] = av; ad2[node] = dv; }
}

// ---------------- layer-2 aggregation + log_softmax ----------------

__global__ __launch_bounds__(256) void l2agg_k(const float* __restrict__ h2, const float* __restrict__ as2,
                                               const float* __restrict__ ad2, const float* __restrict__ b2,
                                               const int* __restrict__ rowptr, const int* __restrict__ col,
                                               float* __restrict__ out, int n) {
    __shared__ float ws_all[4][64];
    __shared__ int   ss_all[4][64];
    int wid = threadIdx.x >> 6, lane = threadIdx.x & 63;
    int node = blockIdx.x * 4 + wid;
    if (node >= n) return;
    bool act = lane < NCLS;
    int st = rowptr[node], en = rowptr[node + 1];
    int deg = en - st;
    float z;
    if (deg <= 64) {
        float* ws = ws_all[wid];
        int*   ss = ss_all[wid];
        bool v = lane < deg;
        int s = 0; float av = 0.f;
        if (v) {
            s = col[st + lane];
            av = as2[s];
        }
        ss[lane] = s;
        float ad = ad2[node];
        float e0 = av + ad;
        float ee = v ? (e0 >= 0.f ? e0 : NEG * e0) : -1e30f;
        float m = ee;
#pragma unroll
        for (int off = 1; off < 64; off <<= 1) m = fmaxf(m, __shfl_xor(m, off));
        float p = __expf(ee - m);
        float d = p;
#pragma unroll
        for (int off = 1; off < 64; off <<= 1) d += __shfl_xor(d, off);
        ws[lane] = p / (d + 1e-16f);
        __asm__ volatile("s_waitcnt lgkmcnt(0)" ::: "memory");
        __builtin_amdgcn_sched_barrier(0);
        float acc = 0.f;
        for (int g = 0; g < 8; ++g) {
            if (g * 8 >= deg) break;
#pragma unroll
            for (int jj = 0; jj < 8; ++jj) {
                int j = g * 8 + jj;
                if (j < deg && act)
                    acc += ws[j] * h2[(size_t)ss[j] * NCLS + lane];
            }
        }
        z = act ? acc + b2[lane] : -1e30f;
    } else {
        float ad = ad2[node];
        float m = -1e30f, den = 0.f, acc = 0.f;
        for (int e = st; e < en; ++e) {
            int s = col[e];
            float e0 = as2[s] + ad;
            float ee = e0 >= 0.f ? e0 : NEG * e0;
            float hv = act ? h2[(size_t)s * NCLS + lane] : 0.f;
            float mn = fmaxf(m, ee);
            float sc = __expf(m - mn), p = __expf(ee - mn);
            den = den * sc + p;
            acc = acc * sc + p * hv;
            m = mn;
        }
        z = act ? (acc / (den + 1e-16f) + b2[lane]) : -1e30f;
    }
    float zm = z;
#pragma unroll
    for (int off = 32; off > 0; off >>= 1) zm = fmaxf(zm, __shfl_xor(zm, off));
    float ex = act ? __expf(z - zm) : 0.f;
    float ss2 = ex;
#pragma unroll
    for (int off = 32; off > 0; off >>= 1) ss2 += __shfl_xor(ss2, off);
    if (act) out[(size_t)node * NCLS + lane] = z - zm - logf(ss2);
}

// ---------------- host ----------------

extern "C" void kernel_launch(void* const* d_in, const int* in_sizes, int n_in,
                              void* d_out, int out_size, void* d_ws, size_t ws_size,
                              hipStream_t stream) {
    const float* x    = (const float*)d_in[0];
    const int*   ei   = (const int*)d_in[1];
    const float* W1   = (const float*)d_in[2];
    const float* asw1 = (const float*)d_in[3];
    const float* adw1 = (const float*)d_in[4];
    const float* b1   = (const float*)d_in[5];
    const float* W2   = (const float*)d_in[6];
    const float* asw2 = (const float*)d_in[7];
    const float* adw2 = (const float*)d_in[8];
    const float* b2   = (const float*)d_in[9];
    float* out = (float*)d_out;

    const int n = in_sizes[0] / F_IN;          // 100000
    const int E = in_sizes[1] / 2;             // 1600000
    const int Etot = E + n;
    const int nbuck = (n + DPB - 1) / DPB;     // 391

    char* ws = (char*)d_ws;
    size_t off = 0;
    auto alloc = [&](size_t bytes) -> void* {
        void* p = ws + off;
        off = (off + bytes + 255) & ~(size_t)255;
        return p;
    };
    int*   gcur   = (int*)alloc((size_t)nbuck * 4);
    int*   bbase  = (int*)alloc((size_t)nbuck * 4);
    int*   rowptr = (int*)alloc((size_t)(n + 1) * 4);
    int*   col    = (int*)alloc((size_t)Etot * 4);
    float* h1     = (float*)alloc((size_t)n * HOUT * 4);   // reused for h2/as2/ad2 after l1agg
    float* as1    = (float*)alloc((size_t)n * HEADS * 4);
    float* ad1    = (float*)alloc((size_t)n * HEADS * 4);
    float* hact   = (float*)alloc((size_t)n * HOUT * 4);
    // staging buckets alias hact (dead until l1agg writes it): nbuck*CAP*8 = 25.2MB <= 25.6MB
    int2*  bkt = (int2*)hact;
    float* h2  = h1;
    float* as2 = h1 + (size_t)n * NCLS;
    float* ad2 = h1 + (size_t)n * (NCLS + 1);

    // CSR build (independent of gemm1 chain until l1agg)
    init_k<<<(nbuck + 511) / 512, 512, 0, stream>>>(gcur, nbuck);
    passA_k<<<(Etot + 256 * EPT - 1) / (256 * EPT), 256, 0, stream>>>(ei, gcur, bkt, E, Etot, nbuck);
    bscan_k<<<1, 512, 0, stream>>>(gcur, bbase, rowptr, nbuck, n, Etot);
    passB_k<<<nbuck, 256, 0, stream>>>(bkt, gcur, bbase, rowptr, col, n);

    gemm1_k<<<(n + 127) / 128, 256, 0, stream>>>(x, W1, h1, n);
    att1_k<<<(n * HEADS + 255) / 256, 256, 0, stream>>>(h1, asw1, adw1, as1, ad1, n);
    l1agg_k<<<(n + 3) / 4, 256, 0, stream>>>(h1, as1, ad1, b1, rowptr, col, hact, n);
    g2_k<<<(n + 3) / 4, 256, 0, stream>>>(hact, W2, asw2, adw2, h2, as2, ad2, n);
    l2agg_k<<<(n + 3) / 4, 256, 0, stream>>>(h2, as2, ad2, b2, rowptr, col, out, n);
}

// Round 5
// 477.973 us; speedup vs baseline: 1.6815x; 1.1181x over previous
//
#include <hip/hip_runtime.h>
#include <hip/hip_bf16.h>
#include <math.h>

#define F_IN 512
#define HOUT 64      // HEADS*C1
#define HEADS 8
#define C1 8
#define NCLS 40
#define NEG 0.2f

#define DPB 256            // dsts per bucket
#define CAP 8064           // staging capacity per bucket
#define EPT 32             // edges per thread in passA
#define WLD 520            // padded K-stride of transposed bf16 W1 (512 + 8)

typedef __attribute__((ext_vector_type(8))) short short8;
typedef __attribute__((ext_vector_type(4))) float f32x4;

__device__ __forceinline__ ushort f2b(float f) {
    union { float f; unsigned u; } v; v.f = f;
    unsigned r = (v.u + 0x7FFFu + ((v.u >> 16) & 1u)) >> 16;   // RNE
    return (ushort)r;
}
__device__ __forceinline__ float b2f(ushort b) {
    union { unsigned u; float f; } v; v.u = ((unsigned)b) << 16;
    return v.f;
}

// ---------------- CSR build: bucketed counting sort ----------------

__global__ __launch_bounds__(512) void init_k(int* __restrict__ gcur, int nbuck) {
    int b = blockIdx.x * 512 + threadIdx.x;
    if (b < nbuck) gcur[b] = b * CAP;
}

__global__ __launch_bounds__(256) void passA_k(const int* __restrict__ ei, int* __restrict__ gcur,
                                               int2* __restrict__ bkt, int E, int Etot, int nbuck) {
    __shared__ int hist[512];
    __shared__ int lbase[512];
    int t = threadIdx.x;
    int base_e = blockIdx.x * (256 * EPT);
    for (int j = t; j < nbuck; j += 256) hist[j] = 0;
    __syncthreads();
    int s[EPT], d[EPT];
#pragma unroll
    for (int j = 0; j < EPT; ++j) {
        int idx = base_e + j * 256 + t;
        if (idx < Etot) {
            if (idx < E) { s[j] = ei[idx]; d[j] = ei[E + idx]; }
            else         { s[j] = idx - E; d[j] = idx - E; }
            atomicAdd(&hist[d[j] >> 8], 1);
        } else { s[j] = -1; d[j] = 0; }
    }
    __syncthreads();
    for (int j = t; j < nbuck; j += 256) {
        int c = hist[j];
        lbase[j] = c ? atomicAdd(&gcur[j], c) : 0;
    }
    __syncthreads();
    for (int j = t; j < nbuck; j += 256) hist[j] = 0;
    __syncthreads();
#pragma unroll
    for (int j = 0; j < EPT; ++j) {
        if (s[j] >= 0) {
            int b = d[j] >> 8;
            int slot = atomicAdd(&hist[b], 1);
            bkt[lbase[b] + slot] = make_int2(s[j], d[j]);
        }
    }
}

__global__ __launch_bounds__(512) void bscan_k(const int* __restrict__ gcur, int* __restrict__ bbase,
                                               int* __restrict__ rowptr, int nbuck, int n, int Etot) {
    __shared__ int wsum[8];
    int t = threadIdx.x;
    int v = (t < nbuck) ? gcur[t] - t * CAP : 0;
    int lane = t & 63, w = t >> 6;
    int ss = v;
#pragma unroll
    for (int off = 1; off < 64; off <<= 1) { int t2 = __shfl_up(ss, off); if (lane >= off) ss += t2; }
    if (lane == 63) wsum[w] = ss;
    __syncthreads();
    int woff = 0;
    for (int j = 0; j < w; ++j) woff += wsum[j];
    if (t < nbuck) bbase[t] = woff + ss - v;
    if (t == 0) rowptr[n] = Etot;
}

__global__ __launch_bounds__(256) void passB_k(const int2* __restrict__ bkt, const int* __restrict__ gcur,
                                               const int* __restrict__ bbase, int* __restrict__ rowptr,
                                               int* __restrict__ col, int n) {
    __shared__ int hist[DPB];
    __shared__ int lcur[DPB];
    __shared__ int wsum[4];
    int b = blockIdx.x;
    int t = threadIdx.x;
    int cnt = gcur[b] - b * CAP;
    int base = bbase[b];
    int d0 = b * DPB;
    int ndst = min(DPB, n - d0);
    const int2* src = bkt + (size_t)b * CAP;
    hist[t] = 0;
    __syncthreads();
    for (int e = t; e < cnt; e += 256) {
        int2 v = src[e];
        atomicAdd(&hist[v.y - d0], 1);
    }
    __syncthreads();
    int v = hist[t];
    int lane = t & 63, w = t >> 6;
    int ss = v;
#pragma unroll
    for (int off = 1; off < 64; off <<= 1) { int t2 = __shfl_up(ss, off); if (lane >= off) ss += t2; }
    if (lane == 63) wsum[w] = ss;
    __syncthreads();
    int woff = 0;
    for (int j = 0; j < w; ++j) woff += wsum[j];
    int excl = woff + ss - v;
    if (t < ndst) rowptr[d0 + t] = base + excl;
    lcur[t] = excl;
    __syncthreads();
    for (int e = t; e < cnt; e += 256) {
        int2 v2 = src[e];
        int pos = atomicAdd(&lcur[v2.y - d0], 1);
        col[base + pos] = v2.x;
    }
}

// ---------------- W1 -> transposed bf16 (Wt[c][k], padded stride) ----------------

__global__ __launch_bounds__(256) void wconv_k(const float* __restrict__ W, ushort* __restrict__ Wtg) {
    int idx = blockIdx.x * 256 + threadIdx.x;
    if (idx >= F_IN * HOUT) return;
    int k = idx >> 6, c = idx & 63;
    Wtg[(size_t)c * WLD + k] = f2b(W[idx]);
}

// ---------------- Layer 1 GEMM (bf16 MFMA): h1b[n,64] = bf16(x) @ bf16(W1) ----------------
// 128-row tile, 4 waves; wave w: rows w*32..w*32+31, all 64 cols.
// A staged fp32->bf16 in LDS [128][40] (pad: 2-way-max bank conflict); B frags from L2-resident Wtg.

__global__ __launch_bounds__(256) void gemm1_k(const float* __restrict__ x, const ushort* __restrict__ Wtg,
                                               ushort* __restrict__ h1b, int n) {
    __shared__ ushort Asd[128][40];
    int tid = threadIdx.x;
    int lane = tid & 63, wid = tid >> 6;
    int lr = lane & 15, lg = lane >> 4;
    int row0 = blockIdx.x * 128;
    f32x4 acc[2][4];
#pragma unroll
    for (int rt = 0; rt < 2; ++rt)
#pragma unroll
        for (int ct = 0; ct < 4; ++ct) acc[rt][ct] = (f32x4){0.f, 0.f, 0.f, 0.f};

    for (int k0 = 0; k0 < F_IN; k0 += 32) {
#pragma unroll
        for (int j = 0; j < 4; ++j) {
            int idx = tid + j * 256;        // 0..1023
            int r = idx >> 3;               // 0..127
            int k4 = (idx & 7) << 2;        // 0..28
            int gr = row0 + r;
            float4 v = (gr < n) ? *(const float4*)&x[(size_t)gr * F_IN + k0 + k4]
                                : make_float4(0.f, 0.f, 0.f, 0.f);
            ushort4 b4 = make_ushort4(f2b(v.x), f2b(v.y), f2b(v.z), f2b(v.w));
            *(ushort4*)&Asd[r][k4] = b4;
        }
        __syncthreads();
        short8 af[2], bf[4];
#pragma unroll
        for (int rt = 0; rt < 2; ++rt)
            af[rt] = *(const short8*)&Asd[wid * 32 + rt * 16 + lr][lg * 8];
#pragma unroll
        for (int ct = 0; ct < 4; ++ct)
            bf[ct] = *(const short8*)&Wtg[(size_t)(ct * 16 + lr) * WLD + k0 + lg * 8];
#pragma unroll
        for (int rt = 0; rt < 2; ++rt)
#pragma unroll
            for (int ct = 0; ct < 4; ++ct)
                acc[rt][ct] = __builtin_amdgcn_mfma_f32_16x16x32_bf16(af[rt], bf[ct], acc[rt][ct], 0, 0, 0);
        __syncthreads();
    }
    // epilogue: D[row=(lane>>4)*4+q][col=lane&15] per 16x16 tile
#pragma unroll
    for (int rt = 0; rt < 2; ++rt)
#pragma unroll
        for (int q = 0; q < 4; ++q) {
            int gr = row0 + wid * 32 + rt * 16 + lg * 4 + q;
            if (gr < n) {
#pragma unroll
                for (int ct = 0; ct < 4; ++ct)
                    h1b[(size_t)gr * HOUT + ct * 16 + lr] = f2b(acc[rt][ct][q]);
            }
        }
}

// ---------------- attention dot products layer 1 (reads bf16 h1) ----------------

__global__ void att1_k(const ushort* __restrict__ h1b, const float* __restrict__ asw,
                       const float* __restrict__ adw, float* __restrict__ as1,
                       float* __restrict__ ad1, int n) {
    int t = blockIdx.x * blockDim.x + threadIdx.x;
    if (t >= n * HEADS) return;
    int hd = t & 7;
    const ushort* hp = h1b + (size_t)(t >> 3) * HOUT + hd * C1;
    short8 hv = *(const short8*)hp;
    float4 a0 = *(const float4*)(asw + hd * C1), a1 = *(const float4*)(asw + hd * C1 + 4);
    float4 d0 = *(const float4*)(adw + hd * C1), d1 = *(const float4*)(adw + hd * C1 + 4);
    float h0 = b2f((ushort)hv[0]), h1 = b2f((ushort)hv[1]), h2 = b2f((ushort)hv[2]), h3 = b2f((ushort)hv[3]);
    float h4 = b2f((ushort)hv[4]), h5 = b2f((ushort)hv[5]), h6 = b2f((ushort)hv[6]), h7 = b2f((ushort)hv[7]);
    as1[t] = h0*a0.x + h1*a0.y + h2*a0.z + h3*a0.w + h4*a1.x + h5*a1.y + h6*a1.z + h7*a1.w;
    ad1[t] = h0*d0.x + h1*d0.y + h2*d0.z + h3*d0.w + h4*d1.x + h5*d1.y + h6*d1.z + h7*d1.w;
}

// ---------------- layer-1 aggregation: wave per node, lane-parallel edges ----------------

__global__ __launch_bounds__(256) void l1agg_k(const ushort* __restrict__ h1b, const float* __restrict__ as1,
                                               const float* __restrict__ ad1, const float* __restrict__ b1,
                                               const int* __restrict__ rowptr, const int* __restrict__ col,
                                               ushort* __restrict__ hactb, int n) {
    __shared__ float ws_all[4][8 * 68];
    __shared__ int   ss_all[4][64];
    int wid = threadIdx.x >> 6, lane = threadIdx.x & 63;
    int node = blockIdx.x * 4 + wid;
    if (node >= n) return;
    int st = rowptr[node], en = rowptr[node + 1];
    int deg = en - st;
    float o;
    if (deg <= 64) {
        float* ws = ws_all[wid];
        int*   ss = ss_all[wid];
        bool v = lane < deg;
        int s = 0;
        float4 a0 = make_float4(0.f, 0.f, 0.f, 0.f), a1 = a0;
        if (v) {
            s = col[st + lane];
            a0 = *(const float4*)&as1[s * 8];
            a1 = *(const float4*)&as1[s * 8 + 4];
        }
        ss[lane] = s;
        float4 d0 = *(const float4*)&ad1[node * 8];
        float4 d1 = *(const float4*)&ad1[node * 8 + 4];
        float ea[8] = {a0.x + d0.x, a0.y + d0.y, a0.z + d0.z, a0.w + d0.w,
                       a1.x + d1.x, a1.y + d1.y, a1.z + d1.z, a1.w + d1.w};
#pragma unroll
        for (int h = 0; h < 8; ++h) {
            float e0 = ea[h];
            float ee = v ? (e0 >= 0.f ? e0 : NEG * e0) : -1e30f;
            ws[h * 68 + lane] = ee;
        }
        __asm__ volatile("s_waitcnt lgkmcnt(0)" ::: "memory");
        __builtin_amdgcn_sched_barrier(0);
        {
            int h = lane >> 3, t = lane & 7;
            float e[8];
#pragma unroll
            for (int u = 0; u < 8; ++u) e[u] = ws[h * 68 + t + 8 * u];
            float mx = e[0];
#pragma unroll
            for (int u = 1; u < 8; ++u) mx = fmaxf(mx, e[u]);
            mx = fmaxf(mx, __shfl_xor(mx, 1));
            mx = fmaxf(mx, __shfl_xor(mx, 2));
            mx = fmaxf(mx, __shfl_xor(mx, 4));
            float p[8], sm = 0.f;
#pragma unroll
            for (int u = 0; u < 8; ++u) { p[u] = __expf(e[u] - mx); sm += p[u]; }
            sm += __shfl_xor(sm, 1);
            sm += __shfl_xor(sm, 2);
            sm += __shfl_xor(sm, 4);
            float inv = 1.f / (sm + 1e-16f);
#pragma unroll
            for (int u = 0; u < 8; ++u) ws[h * 68 + t + 8 * u] = p[u] * inv;
        }
        __asm__ volatile("s_waitcnt lgkmcnt(0)" ::: "memory");
        __builtin_amdgcn_sched_barrier(0);
        int chd = lane >> 3;
        float acc = 0.f;
        for (int g = 0; g < 16; ++g) {
            if (g * 4 >= deg) break;
#pragma unroll
            for (int jj = 0; jj < 4; ++jj) {
                int j = g * 4 + jj;
                if (j < deg)
                    acc += ws[chd * 68 + j] * b2f(h1b[(size_t)ss[j] * HOUT + lane]);
            }
        }
        o = acc + b1[lane];
    } else {
        int hd = lane >> 3;
        float ad = ad1[node * HEADS + hd];
        float m = -1e30f, den = 0.f, acc = 0.f;
        for (int e = st; e < en; ++e) {
            int s = col[e];
            float e0 = as1[s * HEADS + hd] + ad;
            float ee = e0 >= 0.f ? e0 : NEG * e0;
            float hv = b2f(h1b[(size_t)s * HOUT + lane]);
            float mn = fmaxf(m, ee);
            float sc = __expf(m - mn), p = __expf(ee - mn);
            den = den * sc + p;
            acc = acc * sc + p * hv;
            m = mn;
        }
        o = acc / (den + 1e-16f) + b1[lane];
    }
    float e = o > 0.f ? o : expm1f(o);   // ELU
    hactb[(size_t)node * HOUT + lane] = f2b(e);
}

// ---------------- layer-2 GEMM (64->40) + attention dots ----------------

__global__ __launch_bounds__(256) void g2_k(const ushort* __restrict__ hactb, const float* __restrict__ W2,
                                            const float* __restrict__ asw, const float* __restrict__ adw,
                                            ushort* __restrict__ h2b, float* __restrict__ as2,
                                            float* __restrict__ ad2, int n) {
    __shared__ float W2s[HOUT * NCLS];
    for (int t = threadIdx.x; t < HOUT * NCLS; t += 256) W2s[t] = W2[t];
    __syncthreads();
    int lane = threadIdx.x & 63;
    int node = blockIdx.x * 4 + (threadIdx.x >> 6);
    if (node >= n) return;
    float hreg = b2f(hactb[(size_t)node * HOUT + lane]);
    int cc = lane < NCLS ? lane : 0;
    float o = 0.f;
#pragma unroll
    for (int k = 0; k < HOUT; ++k) {
        float hk = __shfl(hreg, k);
        o += hk * W2s[k * NCLS + cc];
    }
    float av = lane < NCLS ? o * asw[lane] : 0.f;
    float dv = lane < NCLS ? o * adw[lane] : 0.f;
#pragma unroll
    for (int off = 32; off > 0; off >>= 1) {
        av += __shfl_xor(av, off);
        dv += __shfl_xor(dv, off);
    }
    if (lane < NCLS) h2b[(size_t)node * NCLS + lane] = f2b(o);
    if (lane == 0) { as2[node] = av; ad2[node] = dv; }
}

// ---------------- layer-2 aggregation + log_softmax ----------------

__global__ __launch_bounds__(256) void l2agg_k(const ushort* __restrict__ h2b, const float* __restrict__ as2,
                                               const float* __restrict__ ad2, const float* __restrict__ b2,
                                               const int* __restrict__ rowptr, const int* __restrict__ col,
                                               float* __restrict__ out, int n) {
    __shared__ float ws_all[4][64];
    __shared__ int   ss_all[4][64];
    int wid = threadIdx.x >> 6, lane = threadIdx.x & 63;
    int node = blockIdx.x * 4 + wid;
    if (node >= n) return;
    bool act = lane < NCLS;
    int st = rowptr[node], en = rowptr[node + 1];
    int deg = en - st;
    float z;
    if (deg <= 64) {
        float* ws = ws_all[wid];
        int*   ss = ss_all[wid];
        bool v = lane < deg;
        int s = 0; float av = 0.f;
        if (v) {
            s = col[st + lane];
            av = as2[s];
        }
        ss[lane] = s;
        float ad = ad2[node];
        float e0 = av + ad;
        float ee = v ? (e0 >= 0.f ? e0 : NEG * e0) : -1e30f;
        float m = ee;
#pragma unroll
        for (int off = 1; off < 64; off <<= 1) m = fmaxf(m, __shfl_xor(m, off));
        float p = __expf(ee - m);
        float d = p;
#pragma unroll
        for (int off = 1; off < 64; off <<= 1) d += __shfl_xor(d, off);
        ws[lane] = p / (d + 1e-16f);
        __asm__ volatile("s_waitcnt lgkmcnt(0)" ::: "memory");
        __builtin_amdgcn_sched_barrier(0);
        float acc = 0.f;
        for (int g = 0; g < 8; ++g) {
            if (g * 8 >= deg) break;
#pragma unroll
            for (int jj = 0; jj < 8; ++jj) {
                int j = g * 8 + jj;
                if (j < deg && act)
                    acc += ws[j] * b2f(h2b[(size_t)ss[j] * NCLS + lane]);
            }
        }
        z = act ? acc + b2[lane] : -1e30f;
    } else {
        float ad = ad2[node];
        float m = -1e30f, den = 0.f, acc = 0.f;
        for (int e = st; e < en; ++e) {
            int s = col[e];
            float e0 = as2[s] + ad;
            float ee = e0 >= 0.f ? e0 : NEG * e0;
            float hv = act ? b2f(h2b[(size_t)s * NCLS + lane]) : 0.f;
            float mn = fmaxf(m, ee);
            float sc = __expf(m - mn), p = __expf(ee - mn);
            den = den * sc + p;
            acc = acc * sc + p * hv;
            m = mn;
        }
        z = act ? (acc / (den + 1e-16f) + b2[lane]) : -1e30f;
    }
    float zm = z;
#pragma unroll
    for (int off = 32; off > 0; off >>= 1) zm = fmaxf(zm, __shfl_xor(zm, off));
    float ex = act ? __expf(z - zm) : 0.f;
    float ss2 = ex;
#pragma unroll
    for (int off = 32; off > 0; off >>= 1) ss2 += __shfl_xor(ss2, off);
    if (act) out[(size_t)node * NCLS + lane] = z - zm - logf(ss2);
}

// ---------------- host ----------------

extern "C" void kernel_launch(void* const* d_in, const int* in_sizes, int n_in,
                              void* d_out, int out_size, void* d_ws, size_t ws_size,
                              hipStream_t stream) {
    const float* x    = (const float*)d_in[0];
    const int*   ei   = (const int*)d_in[1];
    const float* W1   = (const float*)d_in[2];
    const float* asw1 = (const float*)d_in[3];
    const float* adw1 = (const float*)d_in[4];
    const float* b1   = (const float*)d_in[5];
    const float* W2   = (const float*)d_in[6];
    const float* asw2 = (const float*)d_in[7];
    const float* adw2 = (const float*)d_in[8];
    const float* b2   = (const float*)d_in[9];
    float* out = (float*)d_out;

    const int n = in_sizes[0] / F_IN;          // 100000
    const int E = in_sizes[1] / 2;             // 1600000
    const int Etot = E + n;
    const int nbuck = (n + DPB - 1) / DPB;     // 391

    char* ws = (char*)d_ws;
    size_t off = 0;
    auto alloc = [&](size_t bytes) -> void* {
        void* p = ws + off;
        off = (off + bytes + 255) & ~(size_t)255;
        return p;
    };
    int*    gcur   = (int*)alloc((size_t)nbuck * 4);
    int*    bbase  = (int*)alloc((size_t)nbuck * 4);
    int*    rowptr = (int*)alloc((size_t)(n + 1) * 4);
    int*    col    = (int*)alloc((size_t)Etot * 4);
    int2*   bkt    = (int2*)alloc((size_t)nbuck * CAP * 8);          // 25.2 MB
    ushort* h1b    = (ushort*)alloc((size_t)n * HOUT * 2);           // 12.8 MB (reused below)
    float*  as1    = (float*)alloc((size_t)n * HEADS * 4);
    float*  ad1    = (float*)alloc((size_t)n * HEADS * 4);
    ushort* hactb  = (ushort*)alloc((size_t)n * HOUT * 2);           // 12.8 MB
    ushort* Wtg    = (ushort*)alloc((size_t)HOUT * WLD * 2);         // 66.6 KB
    // aliases into h1b's region (h1b dead after l1agg): h2b 8MB + as2/ad2 0.8MB <= 12.8MB
    ushort* h2b = h1b;
    float*  as2 = (float*)(h1b + (size_t)n * NCLS);
    float*  ad2 = as2 + n;

    // CSR build (independent of the gemm chain until l1agg)
    init_k<<<(nbuck + 511) / 512, 512, 0, stream>>>(gcur, nbuck);
    passA_k<<<(Etot + 256 * EPT - 1) / (256 * EPT), 256, 0, stream>>>(ei, gcur, bkt, E, Etot, nbuck);
    bscan_k<<<1, 512, 0, stream>>>(gcur, bbase, rowptr, nbuck, n, Etot);
    passB_k<<<nbuck, 256, 0, stream>>>(bkt, gcur, bbase, rowptr, col, n);

    wconv_k<<<(F_IN * HOUT + 255) / 256, 256, 0, stream>>>(W1, Wtg);
    gemm1_k<<<(n + 127) / 128, 256, 0, stream>>>(x, Wtg, h1b, n);
    att1_k<<<(n * HEADS + 255) / 256, 256, 0, stream>>>(h1b, asw1, adw1, as1, ad1, n);
    l1agg_k<<<(n + 3) / 4, 256, 0, stream>>>(h1b, as1, ad1, b1, rowptr, col, hactb, n);
    g2_k<<<(n + 3) / 4, 256, 0, stream>>>(hactb, W2, asw2, adw2, h2b, as2, ad2, n);
    l2agg_k<<<(n + 3) / 4, 256, 0, stream>>>(h2b, as2, ad2, b2, rowptr, col, out, n);
}

// Round 6
// 379.488 us; speedup vs baseline: 2.1179x; 1.2595x over previous
//
#include <hip/hip_runtime.h>
#include <hip/hip_bf16.h>
#include <math.h>

#define F_IN 512
#define HOUT 64      // HEADS*C1
#define HEADS 8
#define C1 8
#define NCLS 40
#define NEG 0.2f

#define DPB 256            // dsts per bucket
#define CAP 8064           // staging capacity per bucket
#define EPT 32             // edges per thread in passA
#define WLD 520            // padded K-stride of transposed bf16 W1 (512 + 8)

typedef __attribute__((ext_vector_type(8))) short short8;
typedef __attribute__((ext_vector_type(4))) float f32x4;

__device__ __forceinline__ ushort f2b(float f) {
    union { float f; unsigned u; } v; v.f = f;
    unsigned r = (v.u + 0x7FFFu + ((v.u >> 16) & 1u)) >> 16;   // RNE
    return (ushort)r;
}
__device__ __forceinline__ float b2f(ushort b) {
    union { unsigned u; float f; } v; v.u = ((unsigned)b) << 16;
    return v.f;
}

// ---------------- CSR build: bucketed counting sort ----------------

__global__ __launch_bounds__(512) void init_k(int* __restrict__ gcur, int nbuck) {
    int b = blockIdx.x * 512 + threadIdx.x;
    if (b < nbuck) gcur[b] = b * CAP;
}

__global__ __launch_bounds__(256) void passA_k(const int* __restrict__ ei, int* __restrict__ gcur,
                                               int2* __restrict__ bkt, int E, int Etot, int nbuck) {
    __shared__ int hist[512];
    __shared__ int lbase[512];
    int t = threadIdx.x;
    int base_e = blockIdx.x * (256 * EPT);
    for (int j = t; j < nbuck; j += 256) hist[j] = 0;
    __syncthreads();
    int s[EPT], d[EPT];
#pragma unroll
    for (int j = 0; j < EPT; ++j) {
        int idx = base_e + j * 256 + t;
        if (idx < Etot) {
            if (idx < E) { s[j] = ei[idx]; d[j] = ei[E + idx]; }
            else         { s[j] = idx - E; d[j] = idx - E; }
            atomicAdd(&hist[d[j] >> 8], 1);
        } else { s[j] = -1; d[j] = 0; }
    }
    __syncthreads();
    for (int j = t; j < nbuck; j += 256) {
        int c = hist[j];
        lbase[j] = c ? atomicAdd(&gcur[j], c) : 0;
    }
    __syncthreads();
    for (int j = t; j < nbuck; j += 256) hist[j] = 0;
    __syncthreads();
#pragma unroll
    for (int j = 0; j < EPT; ++j) {
        if (s[j] >= 0) {
            int b = d[j] >> 8;
            int slot = atomicAdd(&hist[b], 1);
            bkt[lbase[b] + slot] = make_int2(s[j], d[j]);
        }
    }
}

__global__ __launch_bounds__(512) void bscan_k(const int* __restrict__ gcur, int* __restrict__ bbase,
                                               int* __restrict__ rowptr, int nbuck, int n, int Etot) {
    __shared__ int wsum[8];
    int t = threadIdx.x;
    int v = (t < nbuck) ? gcur[t] - t * CAP : 0;
    int lane = t & 63, w = t >> 6;
    int ss = v;
#pragma unroll
    for (int off = 1; off < 64; off <<= 1) { int t2 = __shfl_up(ss, off); if (lane >= off) ss += t2; }
    if (lane == 63) wsum[w] = ss;
    __syncthreads();
    int woff = 0;
    for (int j = 0; j < w; ++j) woff += wsum[j];
    if (t < nbuck) bbase[t] = woff + ss - v;
    if (t == 0) rowptr[n] = Etot;
}

__global__ __launch_bounds__(256) void passB_k(const int2* __restrict__ bkt, const int* __restrict__ gcur,
                                               const int* __restrict__ bbase, int* __restrict__ rowptr,
                                               int* __restrict__ col, int n) {
    __shared__ int hist[DPB];
    __shared__ int lcur[DPB];
    __shared__ int wsum[4];
    int b = blockIdx.x;
    int t = threadIdx.x;
    int cnt = gcur[b] - b * CAP;
    int base = bbase[b];
    int d0 = b * DPB;
    int ndst = min(DPB, n - d0);
    const int2* src = bkt + (size_t)b * CAP;
    hist[t] = 0;
    __syncthreads();
    for (int e = t; e < cnt; e += 256) {
        int2 v = src[e];
        atomicAdd(&hist[v.y - d0], 1);
    }
    __syncthreads();
    int v = hist[t];
    int lane = t & 63, w = t >> 6;
    int ss = v;
#pragma unroll
    for (int off = 1; off < 64; off <<= 1) { int t2 = __shfl_up(ss, off); if (lane >= off) ss += t2; }
    if (lane == 63) wsum[w] = ss;
    __syncthreads();
    int woff = 0;
    for (int j = 0; j < w; ++j) woff += wsum[j];
    int excl = woff + ss - v;
    if (t < ndst) rowptr[d0 + t] = base + excl;
    lcur[t] = excl;
    __syncthreads();
    for (int e = t; e < cnt; e += 256) {
        int2 v2 = src[e];
        int pos = atomicAdd(&lcur[v2.y - d0], 1);
        col[base + pos] = v2.x;
    }
}

// ---------------- W1 -> transposed bf16 (Wt[c][k], padded stride) ----------------

__global__ __launch_bounds__(256) void wconv_k(const float* __restrict__ W, ushort* __restrict__ Wtg) {
    int idx = blockIdx.x * 256 + threadIdx.x;
    if (idx >= F_IN * HOUT) return;
    int k = idx >> 6, c = idx & 63;
    Wtg[(size_t)c * WLD + k] = f2b(W[idx]);
}

// ---------------- W2 -> transposed bf16 W2t[48][64] (cols 40..47 zero) ----------------

__global__ __launch_bounds__(256) void w2conv_k(const float* __restrict__ W2, ushort* __restrict__ W2t) {
    int idx = blockIdx.x * 256 + threadIdx.x;
    if (idx >= 48 * HOUT) return;
    int c = idx >> 6, k = idx & 63;
    W2t[idx] = (c < NCLS) ? f2b(W2[k * NCLS + c]) : 0;
}

// ---------------- Layer 1 GEMM (bf16 MFMA): h1b[n,64] = bf16(x) @ bf16(W1) ----------------

__global__ __launch_bounds__(256) void gemm1_k(const float* __restrict__ x, const ushort* __restrict__ Wtg,
                                               ushort* __restrict__ h1b, int n) {
    __shared__ ushort Asd[128][40];
    int tid = threadIdx.x;
    int lane = tid & 63, wid = tid >> 6;
    int lr = lane & 15, lg = lane >> 4;
    int row0 = blockIdx.x * 128;
    f32x4 acc[2][4];
#pragma unroll
    for (int rt = 0; rt < 2; ++rt)
#pragma unroll
        for (int ct = 0; ct < 4; ++ct) acc[rt][ct] = (f32x4){0.f, 0.f, 0.f, 0.f};

    for (int k0 = 0; k0 < F_IN; k0 += 32) {
#pragma unroll
        for (int j = 0; j < 4; ++j) {
            int idx = tid + j * 256;        // 0..1023
            int r = idx >> 3;               // 0..127
            int k4 = (idx & 7) << 2;        // 0..28
            int gr = row0 + r;
            float4 v = (gr < n) ? *(const float4*)&x[(size_t)gr * F_IN + k0 + k4]
                                : make_float4(0.f, 0.f, 0.f, 0.f);
            ushort4 b4 = make_ushort4(f2b(v.x), f2b(v.y), f2b(v.z), f2b(v.w));
            *(ushort4*)&Asd[r][k4] = b4;
        }
        __syncthreads();
        short8 af[2], bf[4];
#pragma unroll
        for (int rt = 0; rt < 2; ++rt)
            af[rt] = *(const short8*)&Asd[wid * 32 + rt * 16 + lr][lg * 8];
#pragma unroll
        for (int ct = 0; ct < 4; ++ct)
            bf[ct] = *(const short8*)&Wtg[(size_t)(ct * 16 + lr) * WLD + k0 + lg * 8];
#pragma unroll
        for (int rt = 0; rt < 2; ++rt)
#pragma unroll
            for (int ct = 0; ct < 4; ++ct)
                acc[rt][ct] = __builtin_amdgcn_mfma_f32_16x16x32_bf16(af[rt], bf[ct], acc[rt][ct], 0, 0, 0);
        __syncthreads();
    }
#pragma unroll
    for (int rt = 0; rt < 2; ++rt)
#pragma unroll
        for (int q = 0; q < 4; ++q) {
            int gr = row0 + wid * 32 + rt * 16 + lg * 4 + q;
            if (gr < n) {
#pragma unroll
                for (int ct = 0; ct < 4; ++ct)
                    h1b[(size_t)gr * HOUT + ct * 16 + lr] = f2b(acc[rt][ct][q]);
            }
        }
}

// ---------------- attention dot products layer 1 (reads bf16 h1) ----------------

__global__ void att1_k(const ushort* __restrict__ h1b, const float* __restrict__ asw,
                       const float* __restrict__ adw, float* __restrict__ as1,
                       float* __restrict__ ad1, int n) {
    int t = blockIdx.x * blockDim.x + threadIdx.x;
    if (t >= n * HEADS) return;
    int hd = t & 7;
    const ushort* hp = h1b + (size_t)(t >> 3) * HOUT + hd * C1;
    short8 hv = *(const short8*)hp;
    float4 a0 = *(const float4*)(asw + hd * C1), a1 = *(const float4*)(asw + hd * C1 + 4);
    float4 d0 = *(const float4*)(adw + hd * C1), d1 = *(const float4*)(adw + hd * C1 + 4);
    float h0 = b2f((ushort)hv[0]), h1 = b2f((ushort)hv[1]), h2 = b2f((ushort)hv[2]), h3 = b2f((ushort)hv[3]);
    float h4 = b2f((ushort)hv[4]), h5 = b2f((ushort)hv[5]), h6 = b2f((ushort)hv[6]), h7 = b2f((ushort)hv[7]);
    as1[t] = h0*a0.x + h1*a0.y + h2*a0.z + h3*a0.w + h4*a1.x + h5*a1.y + h6*a1.z + h7*a1.w;
    ad1[t] = h0*d0.x + h1*d0.y + h2*d0.z + h3*d0.w + h4*d1.x + h5*d1.y + h6*d1.z + h7*d1.w;
}

// ---------------- layer-1 aggregation: wave per node, lane-parallel edges ----------------

__global__ __launch_bounds__(256) void l1agg_k(const ushort* __restrict__ h1b, const float* __restrict__ as1,
                                               const float* __restrict__ ad1, const float* __restrict__ b1,
                                               const int* __restrict__ rowptr, const int* __restrict__ col,
                                               ushort* __restrict__ hactb, int n) {
    __shared__ float ws_all[4][8 * 68];
    __shared__ int   ss_all[4][64];
    int wid = threadIdx.x >> 6, lane = threadIdx.x & 63;
    int node = blockIdx.x * 4 + wid;
    if (node >= n) return;
    int st = rowptr[node], en = rowptr[node + 1];
    int deg = en - st;
    float o;
    if (deg <= 64) {
        float* ws = ws_all[wid];
        int*   ss = ss_all[wid];
        bool v = lane < deg;
        int s = 0;
        float4 a0 = make_float4(0.f, 0.f, 0.f, 0.f), a1 = a0;
        if (v) {
            s = col[st + lane];
            a0 = *(const float4*)&as1[s * 8];
            a1 = *(const float4*)&as1[s * 8 + 4];
        }
        ss[lane] = s;
        float4 d0 = *(const float4*)&ad1[node * 8];
        float4 d1 = *(const float4*)&ad1[node * 8 + 4];
        float ea[8] = {a0.x + d0.x, a0.y + d0.y, a0.z + d0.z, a0.w + d0.w,
                       a1.x + d1.x, a1.y + d1.y, a1.z + d1.z, a1.w + d1.w};
#pragma unroll
        for (int h = 0; h < 8; ++h) {
            float e0 = ea[h];
            float ee = v ? (e0 >= 0.f ? e0 : NEG * e0) : -1e30f;
            ws[h * 68 + lane] = ee;
        }
        __asm__ volatile("s_waitcnt lgkmcnt(0)" ::: "memory");
        __builtin_amdgcn_sched_barrier(0);
        {
            int h = lane >> 3, t = lane & 7;
            float e[8];
#pragma unroll
            for (int u = 0; u < 8; ++u) e[u] = ws[h * 68 + t + 8 * u];
            float mx = e[0];
#pragma unroll
            for (int u = 1; u < 8; ++u) mx = fmaxf(mx, e[u]);
            mx = fmaxf(mx, __shfl_xor(mx, 1));
            mx = fmaxf(mx, __shfl_xor(mx, 2));
            mx = fmaxf(mx, __shfl_xor(mx, 4));
            float p[8], sm = 0.f;
#pragma unroll
            for (int u = 0; u < 8; ++u) { p[u] = __expf(e[u] - mx); sm += p[u]; }
            sm += __shfl_xor(sm, 1);
            sm += __shfl_xor(sm, 2);
            sm += __shfl_xor(sm, 4);
            float inv = 1.f / (sm + 1e-16f);
#pragma unroll
            for (int u = 0; u < 8; ++u) ws[h * 68 + t + 8 * u] = p[u] * inv;
        }
        __asm__ volatile("s_waitcnt lgkmcnt(0)" ::: "memory");
        __builtin_amdgcn_sched_barrier(0);
        int chd = lane >> 3;
        float acc = 0.f;
        for (int g = 0; g < 16; ++g) {
            if (g * 4 >= deg) break;
#pragma unroll
            for (int jj = 0; jj < 4; ++jj) {
                int j = g * 4 + jj;
                if (j < deg)
                    acc += ws[chd * 68 + j] * b2f(h1b[(size_t)ss[j] * HOUT + lane]);
            }
        }
        o = acc + b1[lane];
    } else {
        int hd = lane >> 3;
        float ad = ad1[node * HEADS + hd];
        float m = -1e30f, den = 0.f, acc = 0.f;
        for (int e = st; e < en; ++e) {
            int s = col[e];
            float e0 = as1[s * HEADS + hd] + ad;
            float ee = e0 >= 0.f ? e0 : NEG * e0;
            float hv = b2f(h1b[(size_t)s * HOUT + lane]);
            float mn = fmaxf(m, ee);
            float sc = __expf(m - mn), p = __expf(ee - mn);
            den = den * sc + p;
            acc = acc * sc + p * hv;
            m = mn;
        }
        o = acc / (den + 1e-16f) + b1[lane];
    }
    float e = o > 0.f ? o : expm1f(o);   // ELU
    hactb[(size_t)node * HOUT + lane] = f2b(e);
}

// ---------------- layer-2 GEMM (64->40) + attention dots: MFMA, no LDS ----------------
// Wave handles 16 nodes: A = hact rows (16x64 bf16), B = W2t[48][64] (3 col-tiles), 6 MFMAs.

__global__ __launch_bounds__(256) void g2_k(const ushort* __restrict__ hactb, const ushort* __restrict__ W2t,
                                            const float* __restrict__ asw, const float* __restrict__ adw,
                                            ushort* __restrict__ h2b, float* __restrict__ as2,
                                            float* __restrict__ ad2, int n) {
    int tid = threadIdx.x;
    int lane = tid & 63, wid = tid >> 6;
    int lr = lane & 15, lg = lane >> 4;
    int row0 = blockIdx.x * 64 + wid * 16;          // this wave's 16 nodes
    if (row0 >= n) return;
    int gr = row0 + lr;
    bool vr = gr < n;
    f32x4 acc[3];
#pragma unroll
    for (int ct = 0; ct < 3; ++ct) acc[ct] = (f32x4){0.f, 0.f, 0.f, 0.f};
    const short8 z8 = (short8){0, 0, 0, 0, 0, 0, 0, 0};
#pragma unroll
    for (int ks = 0; ks < 2; ++ks) {
        short8 af = vr ? *(const short8*)&hactb[(size_t)gr * HOUT + ks * 32 + lg * 8] : z8;
#pragma unroll
        for (int ct = 0; ct < 3; ++ct) {
            short8 bf = *(const short8*)&W2t[(ct * 16 + lr) * HOUT + ks * 32 + lg * 8];
            acc[ct] = __builtin_amdgcn_mfma_f32_16x16x32_bf16(af, bf, acc[ct], 0, 0, 0);
        }
    }
    // epilogue: lane holds D[row=lg*4+q][col=ct*16+lr]
    float av4[4], dv4[4];
#pragma unroll
    for (int q = 0; q < 4; ++q) {
        int r = row0 + lg * 4 + q;
        bool vw = r < n;
        float av = 0.f, dv = 0.f;
#pragma unroll
        for (int ct = 0; ct < 3; ++ct) {
            int c = ct * 16 + lr;
            if (c < NCLS) {
                float o = acc[ct][q];
                av += o * asw[c];
                dv += o * adw[c];
                if (vw) h2b[(size_t)r * NCLS + c] = f2b(o);
            }
        }
        av += __shfl_xor(av, 1); av += __shfl_xor(av, 2); av += __shfl_xor(av, 4); av += __shfl_xor(av, 8);
        dv += __shfl_xor(dv, 1); dv += __shfl_xor(dv, 2); dv += __shfl_xor(dv, 4); dv += __shfl_xor(dv, 8);
        av4[q] = av; dv4[q] = dv;
    }
#pragma unroll
    for (int q = 0; q < 4; ++q) {
        int r = row0 + lg * 4 + q;
        if (lr == q && r < n) as2[r] = av4[q];
        if (lr == 8 + q && r < n) ad2[r] = dv4[q];
    }
}

// ---------------- layer-2 aggregation + log_softmax ----------------

__global__ __launch_bounds__(256) void l2agg_k(const ushort* __restrict__ h2b, const float* __restrict__ as2,
                                               const float* __restrict__ ad2, const float* __restrict__ b2,
                                               const int* __restrict__ rowptr, const int* __restrict__ col,
                                               float* __restrict__ out, int n) {
    __shared__ float ws_all[4][64];
    __shared__ int   ss_all[4][64];
    int wid = threadIdx.x >> 6, lane = threadIdx.x & 63;
    int node = blockIdx.x * 4 + wid;
    if (node >= n) return;
    bool act = lane < NCLS;
    int st = rowptr[node], en = rowptr[node + 1];
    int deg = en - st;
    float z;
    if (deg <= 64) {
        float* ws = ws_all[wid];
        int*   ss = ss_all[wid];
        bool v = lane < deg;
        int s = 0; float av = 0.f;
        if (v) {
            s = col[st + lane];
            av = as2[s];
        }
        ss[lane] = s;
        float ad = ad2[node];
        float e0 = av + ad;
        float ee = v ? (e0 >= 0.f ? e0 : NEG * e0) : -1e30f;
        float m = ee;
#pragma unroll
        for (int off = 1; off < 64; off <<= 1) m = fmaxf(m, __shfl_xor(m, off));
        float p = __expf(ee - m);
        float d = p;
#pragma unroll
        for (int off = 1; off < 64; off <<= 1) d += __shfl_xor(d, off);
        ws[lane] = p / (d + 1e-16f);
        __asm__ volatile("s_waitcnt lgkmcnt(0)" ::: "memory");
        __builtin_amdgcn_sched_barrier(0);
        float acc = 0.f;
        for (int g = 0; g < 8; ++g) {
            if (g * 8 >= deg) break;
#pragma unroll
            for (int jj = 0; jj < 8; ++jj) {
                int j = g * 8 + jj;
                if (j < deg && act)
                    acc += ws[j] * b2f(h2b[(size_t)ss[j] * NCLS + lane]);
            }
        }
        z = act ? acc + b2[lane] : -1e30f;
    } else {
        float ad = ad2[node];
        float m = -1e30f, den = 0.f, acc = 0.f;
        for (int e = st; e < en; ++e) {
            int s = col[e];
            float e0 = as2[s] + ad;
            float ee = e0 >= 0.f ? e0 : NEG * e0;
            float hv = act ? b2f(h2b[(size_t)s * NCLS + lane]) : 0.f;
            float mn = fmaxf(m, ee);
            float sc = __expf(m - mn), p = __expf(ee - mn);
            den = den * sc + p;
            acc = acc * sc + p * hv;
            m = mn;
        }
        z = act ? (acc / (den + 1e-16f) + b2[lane]) : -1e30f;
    }
    float zm = z;
#pragma unroll
    for (int off = 32; off > 0; off >>= 1) zm = fmaxf(zm, __shfl_xor(zm, off));
    float ex = act ? __expf(z - zm) : 0.f;
    float ss2 = ex;
#pragma unroll
    for (int off = 32; off > 0; off >>= 1) ss2 += __shfl_xor(ss2, off);
    if (act) out[(size_t)node * NCLS + lane] = z - zm - logf(ss2);
}

// ---------------- host ----------------

extern "C" void kernel_launch(void* const* d_in, const int* in_sizes, int n_in,
                              void* d_out, int out_size, void* d_ws, size_t ws_size,
                              hipStream_t stream) {
    const float* x    = (const float*)d_in[0];
    const int*   ei   = (const int*)d_in[1];
    const float* W1   = (const float*)d_in[2];
    const float* asw1 = (const float*)d_in[3];
    const float* adw1 = (const float*)d_in[4];
    const float* b1   = (const float*)d_in[5];
    const float* W2   = (const float*)d_in[6];
    const float* asw2 = (const float*)d_in[7];
    const float* adw2 = (const float*)d_in[8];
    const float* b2   = (const float*)d_in[9];
    float* out = (float*)d_out;

    const int n = in_sizes[0] / F_IN;          // 100000
    const int E = in_sizes[1] / 2;             // 1600000
    const int Etot = E + n;
    const int nbuck = (n + DPB - 1) / DPB;     // 391

    char* ws = (char*)d_ws;
    size_t off = 0;
    auto alloc = [&](size_t bytes) -> void* {
        void* p = ws + off;
        off = (off + bytes + 255) & ~(size_t)255;
        return p;
    };
    int*    gcur   = (int*)alloc((size_t)nbuck * 4);
    int*    bbase  = (int*)alloc((size_t)nbuck * 4);
    int*    rowptr = (int*)alloc((size_t)(n + 1) * 4);
    int*    col    = (int*)alloc((size_t)Etot * 4);
    int2*   bkt    = (int2*)alloc((size_t)nbuck * CAP * 8);          // 25.2 MB
    ushort* h1b    = (ushort*)alloc((size_t)n * HOUT * 2);           // 12.8 MB (reused below)
    float*  as1    = (float*)alloc((size_t)n * HEADS * 4);
    float*  ad1    = (float*)alloc((size_t)n * HEADS * 4);
    ushort* hactb  = (ushort*)alloc((size_t)n * HOUT * 2);           // 12.8 MB
    ushort* Wtg    = (ushort*)alloc((size_t)HOUT * WLD * 2);         // 66.6 KB
    ushort* W2t    = (ushort*)alloc((size_t)48 * HOUT * 2);          // 6 KB
    // aliases into h1b's region (h1b dead after l1agg): h2b 8MB + as2/ad2 0.8MB <= 12.8MB
    ushort* h2b = h1b;
    float*  as2 = (float*)(h1b + (size_t)n * NCLS);
    float*  ad2 = as2 + n;

    // CSR build (independent of the gemm chain until l1agg)
    init_k<<<(nbuck + 511) / 512, 512, 0, stream>>>(gcur, nbuck);
    passA_k<<<(Etot + 256 * EPT - 1) / (256 * EPT), 256, 0, stream>>>(ei, gcur, bkt, E, Etot, nbuck);
    bscan_k<<<1, 512, 0, stream>>>(gcur, bbase, rowptr, nbuck, n, Etot);
    passB_k<<<nbuck, 256, 0, stream>>>(bkt, gcur, bbase, rowptr, col, n);

    wconv_k<<<(F_IN * HOUT + 255) / 256, 256, 0, stream>>>(W1, Wtg);
    w2conv_k<<<(48 * HOUT + 255) / 256, 256, 0, stream>>>(W2, W2t);
    gemm1_k<<<(n + 127) / 128, 256, 0, stream>>>(x, Wtg, h1b, n);
    att1_k<<<(n * HEADS + 255) / 256, 256, 0, stream>>>(h1b, asw1, adw1, as1, ad1, n);
    l1agg_k<<<(n + 3) / 4, 256, 0, stream>>>(h1b, as1, ad1, b1, rowptr, col, hactb, n);
    g2_k<<<(n + 63) / 64, 256, 0, stream>>>(hactb, W2t, asw2, adw2, h2b, as2, ad2, n);
    l2agg_k<<<(n + 3) / 4, 256, 0, stream>>>(h2b, as2, ad2, b2, rowptr, col, out, n);
}

// Round 7
// 277.509 us; speedup vs baseline: 2.8962x; 1.3675x over previous
//
#include <hip/hip_runtime.h>
#include <hip/hip_bf16.h>
#include <math.h>

#define F_IN 512
#define HOUT 64      // HEADS*C1
#define HEADS 8
#define C1 8
#define NCLS 40
#define NEG 0.2f

#define DPB 256            // dsts per bucket
#define CAP 8064           // staging capacity per bucket
#define EPT 32             // edges per thread in passA
#define WLD 520            // padded K-stride of transposed bf16 W1 (512 + 8)

typedef __attribute__((ext_vector_type(8))) short short8;
typedef __attribute__((ext_vector_type(4))) float f32x4;

__device__ __forceinline__ ushort f2b(float f) {
    union { float f; unsigned u; } v; v.f = f;
    unsigned r = (v.u + 0x7FFFu + ((v.u >> 16) & 1u)) >> 16;   // RNE
    return (ushort)r;
}
__device__ __forceinline__ float b2f(ushort b) {
    union { unsigned u; float f; } v; v.u = ((unsigned)b) << 16;
    return v.f;
}
__device__ __forceinline__ float b2f_lo(unsigned u) { union { unsigned u; float f; } v; v.u = u << 16; return v.f; }
__device__ __forceinline__ float b2f_hi(unsigned u) { union { unsigned u; float f; } v; v.u = u & 0xFFFF0000u; return v.f; }

// ---------------- CSR build: bucketed counting sort ----------------

__global__ __launch_bounds__(512) void init_k(int* __restrict__ gcur, int nbuck) {
    int b = blockIdx.x * 512 + threadIdx.x;
    if (b < nbuck) gcur[b] = b * CAP;
}

__global__ __launch_bounds__(256) void passA_k(const int* __restrict__ ei, int* __restrict__ gcur,
                                               int2* __restrict__ bkt, int E, int Etot, int nbuck) {
    __shared__ int hist[512];
    __shared__ int lbase[512];
    int t = threadIdx.x;
    int base_e = blockIdx.x * (256 * EPT);
    for (int j = t; j < nbuck; j += 256) hist[j] = 0;
    __syncthreads();
    int s[EPT], d[EPT];
#pragma unroll
    for (int j = 0; j < EPT; ++j) {
        int idx = base_e + j * 256 + t;
        if (idx < Etot) {
            if (idx < E) { s[j] = ei[idx]; d[j] = ei[E + idx]; }
            else         { s[j] = idx - E; d[j] = idx - E; }
            atomicAdd(&hist[d[j] >> 8], 1);
        } else { s[j] = -1; d[j] = 0; }
    }
    __syncthreads();
    for (int j = t; j < nbuck; j += 256) {
        int c = hist[j];
        lbase[j] = c ? atomicAdd(&gcur[j], c) : 0;
    }
    __syncthreads();
    for (int j = t; j < nbuck; j += 256) hist[j] = 0;
    __syncthreads();
#pragma unroll
    for (int j = 0; j < EPT; ++j) {
        if (s[j] >= 0) {
            int b = d[j] >> 8;
            int slot = atomicAdd(&hist[b], 1);
            bkt[lbase[b] + slot] = make_int2(s[j], d[j]);
        }
    }
}

__global__ __launch_bounds__(512) void bscan_k(const int* __restrict__ gcur, int* __restrict__ bbase,
                                               int* __restrict__ rowptr, int nbuck, int n, int Etot) {
    __shared__ int wsum[8];
    int t = threadIdx.x;
    int v = (t < nbuck) ? gcur[t] - t * CAP : 0;
    int lane = t & 63, w = t >> 6;
    int ss = v;
#pragma unroll
    for (int off = 1; off < 64; off <<= 1) { int t2 = __shfl_up(ss, off); if (lane >= off) ss += t2; }
    if (lane == 63) wsum[w] = ss;
    __syncthreads();
    int woff = 0;
    for (int j = 0; j < w; ++j) woff += wsum[j];
    if (t < nbuck) bbase[t] = woff + ss - v;
    if (t == 0) rowptr[n] = Etot;
}

__global__ __launch_bounds__(256) void passB_k(const int2* __restrict__ bkt, const int* __restrict__ gcur,
                                               const int* __restrict__ bbase, int* __restrict__ rowptr,
                                               int* __restrict__ col, int n) {
    __shared__ int hist[DPB];
    __shared__ int lcur[DPB];
    __shared__ int wsum[4];
    int b = blockIdx.x;
    int t = threadIdx.x;
    int cnt = gcur[b] - b * CAP;
    int base = bbase[b];
    int d0 = b * DPB;
    int ndst = min(DPB, n - d0);
    const int2* src = bkt + (size_t)b * CAP;
    hist[t] = 0;
    __syncthreads();
    for (int e = t; e < cnt; e += 256) {
        int2 v = src[e];
        atomicAdd(&hist[v.y - d0], 1);
    }
    __syncthreads();
    int v = hist[t];
    int lane = t & 63, w = t >> 6;
    int ss = v;
#pragma unroll
    for (int off = 1; off < 64; off <<= 1) { int t2 = __shfl_up(ss, off); if (lane >= off) ss += t2; }
    if (lane == 63) wsum[w] = ss;
    __syncthreads();
    int woff = 0;
    for (int j = 0; j < w; ++j) woff += wsum[j];
    int excl = woff + ss - v;
    if (t < ndst) rowptr[d0 + t] = base + excl;
    lcur[t] = excl;
    __syncthreads();
    for (int e = t; e < cnt; e += 256) {
        int2 v2 = src[e];
        int pos = atomicAdd(&lcur[v2.y - d0], 1);
        col[base + pos] = v2.x;
    }
}

// ---------------- weight conversions ----------------

__global__ __launch_bounds__(256) void wconv_k(const float* __restrict__ W, ushort* __restrict__ Wtg) {
    int idx = blockIdx.x * 256 + threadIdx.x;
    if (idx >= F_IN * HOUT) return;
    int k = idx >> 6, c = idx & 63;
    Wtg[(size_t)c * WLD + k] = f2b(W[idx]);
}

__global__ __launch_bounds__(256) void w2conv_k(const float* __restrict__ W2, ushort* __restrict__ W2t) {
    int idx = blockIdx.x * 256 + threadIdx.x;
    if (idx >= 48 * HOUT) return;
    int c = idx >> 6, k = idx & 63;
    W2t[idx] = (c < NCLS) ? f2b(W2[k * NCLS + c]) : 0;
}

// ---------------- Layer 1 GEMM (bf16 MFMA) ----------------

__global__ __launch_bounds__(256) void gemm1_k(const float* __restrict__ x, const ushort* __restrict__ Wtg,
                                               ushort* __restrict__ h1b, int n) {
    __shared__ ushort Asd[128][40];
    int tid = threadIdx.x;
    int lane = tid & 63, wid = tid >> 6;
    int lr = lane & 15, lg = lane >> 4;
    int row0 = blockIdx.x * 128;
    f32x4 acc[2][4];
#pragma unroll
    for (int rt = 0; rt < 2; ++rt)
#pragma unroll
        for (int ct = 0; ct < 4; ++ct) acc[rt][ct] = (f32x4){0.f, 0.f, 0.f, 0.f};

    for (int k0 = 0; k0 < F_IN; k0 += 32) {
#pragma unroll
        for (int j = 0; j < 4; ++j) {
            int idx = tid + j * 256;
            int r = idx >> 3;
            int k4 = (idx & 7) << 2;
            int gr = row0 + r;
            float4 v = (gr < n) ? *(const float4*)&x[(size_t)gr * F_IN + k0 + k4]
                                : make_float4(0.f, 0.f, 0.f, 0.f);
            ushort4 b4 = make_ushort4(f2b(v.x), f2b(v.y), f2b(v.z), f2b(v.w));
            *(ushort4*)&Asd[r][k4] = b4;
        }
        __syncthreads();
        short8 af[2], bf[4];
#pragma unroll
        for (int rt = 0; rt < 2; ++rt)
            af[rt] = *(const short8*)&Asd[wid * 32 + rt * 16 + lr][lg * 8];
#pragma unroll
        for (int ct = 0; ct < 4; ++ct)
            bf[ct] = *(const short8*)&Wtg[(size_t)(ct * 16 + lr) * WLD + k0 + lg * 8];
#pragma unroll
        for (int rt = 0; rt < 2; ++rt)
#pragma unroll
            for (int ct = 0; ct < 4; ++ct)
                acc[rt][ct] = __builtin_amdgcn_mfma_f32_16x16x32_bf16(af[rt], bf[ct], acc[rt][ct], 0, 0, 0);
        __syncthreads();
    }
#pragma unroll
    for (int rt = 0; rt < 2; ++rt)
#pragma unroll
        for (int q = 0; q < 4; ++q) {
            int gr = row0 + wid * 32 + rt * 16 + lg * 4 + q;
            if (gr < n) {
#pragma unroll
                for (int ct = 0; ct < 4; ++ct)
                    h1b[(size_t)gr * HOUT + ct * 16 + lr] = f2b(acc[rt][ct][q]);
            }
        }
}

// ---------------- attention dot products layer 1 ----------------

__global__ void att1_k(const ushort* __restrict__ h1b, const float* __restrict__ asw,
                       const float* __restrict__ adw, float* __restrict__ as1,
                       float* __restrict__ ad1, int n) {
    int t = blockIdx.x * blockDim.x + threadIdx.x;
    if (t >= n * HEADS) return;
    int hd = t & 7;
    const ushort* hp = h1b + (size_t)(t >> 3) * HOUT + hd * C1;
    short8 hv = *(const short8*)hp;
    float4 a0 = *(const float4*)(asw + hd * C1), a1 = *(const float4*)(asw + hd * C1 + 4);
    float4 d0 = *(const float4*)(adw + hd * C1), d1 = *(const float4*)(adw + hd * C1 + 4);
    float h0 = b2f((ushort)hv[0]), h1 = b2f((ushort)hv[1]), h2 = b2f((ushort)hv[2]), h3 = b2f((ushort)hv[3]);
    float h4 = b2f((ushort)hv[4]), h5 = b2f((ushort)hv[5]), h6 = b2f((ushort)hv[6]), h7 = b2f((ushort)hv[7]);
    as1[t] = h0*a0.x + h1*a0.y + h2*a0.z + h3*a0.w + h4*a1.x + h5*a1.y + h6*a1.z + h7*a1.w;
    ad1[t] = h0*d0.x + h1*d0.y + h2*d0.z + h3*d0.w + h4*d1.x + h5*d1.y + h6*d1.z + h7*d1.w;
}

// ---------------- layer-1 aggregation: 2 nodes/wave, 2 channels/lane ----------------
// Half-wave = one node; 32 edge slots. pk[na][h*34+j] packs (weight, src) as int2.
// Invalid slots get ee=-1e30 -> w=0, so phase 3 needs no per-edge predication.

__global__ __launch_bounds__(256) void l1agg_k(const ushort* __restrict__ h1b, const float* __restrict__ as1,
                                               const float* __restrict__ ad1, const float* __restrict__ b1,
                                               const int* __restrict__ rowptr, const int* __restrict__ col,
                                               ushort* __restrict__ hactb, int n) {
    __shared__ int2 pk_all[4][2 * 273];    // per wave: [na][h*34+j], na stride 273 (bank-stagger)
    int wid = threadIdx.x >> 6, lane = threadIdx.x & 63;
    int nA = (blockIdx.x * 4 + wid) * 2;
    if (nA >= n) return;
    int nB = nA + 1;
    int na = lane >> 5, sl = lane & 31;
    int node = nA + na;
    bool nodev = node < n;
    int r0 = rowptr[nA];
    int r1 = rowptr[nA + 1];
    int r2 = (nB < n) ? rowptr[nB + 1] : r1;
    int degA = r1 - r0, degB = r2 - r1;
    int st  = na ? r1 : r0;
    int deg = na ? degB : degA;
    int2* pk = pk_all[wid];

    if (degA <= 32 && degB <= 32) {
        bool v = nodev && (sl < deg);
        int s = 0;
        float4 a0 = make_float4(0.f, 0.f, 0.f, 0.f), a1 = a0;
        if (v) {
            s = col[st + sl];
            a0 = *(const float4*)&as1[s * 8];
            a1 = *(const float4*)&as1[s * 8 + 4];
        }
        float4 d0 = make_float4(0.f, 0.f, 0.f, 0.f), d1 = d0;
        if (nodev) {
            d0 = *(const float4*)&ad1[node * 8];
            d1 = *(const float4*)&ad1[node * 8 + 4];
        }
        float ea[8] = {a0.x + d0.x, a0.y + d0.y, a0.z + d0.z, a0.w + d0.w,
                       a1.x + d1.x, a1.y + d1.y, a1.z + d1.z, a1.w + d1.w};
#pragma unroll
        for (int h = 0; h < 8; ++h) {
            float e0 = ea[h];
            float ee = v ? (e0 >= 0.f ? e0 : NEG * e0) : -1e30f;
            pk[na * 273 + h * 34 + sl] = make_int2(__float_as_int(ee), s);
        }
        __asm__ volatile("s_waitcnt lgkmcnt(0)" ::: "memory");
        __builtin_amdgcn_sched_barrier(0);
        // phase 2: lane = (na2, h, t): each lane owns 8 slots {t, t+4, ..., t+28}
        {
            int t = lane & 3, h = (lane >> 2) & 7, na2 = lane >> 5;
            int base = na2 * 273 + h * 34;
            float e[8];
#pragma unroll
            for (int u = 0; u < 8; ++u) e[u] = __int_as_float(pk[base + t + 4 * u].x);
            float mx = e[0];
#pragma unroll
            for (int u = 1; u < 8; ++u) mx = fmaxf(mx, e[u]);
            mx = fmaxf(mx, __shfl_xor(mx, 1));
            mx = fmaxf(mx, __shfl_xor(mx, 2));
            float p[8], sm = 0.f;
#pragma unroll
            for (int u = 0; u < 8; ++u) { p[u] = __expf(e[u] - mx); sm += p[u]; }
            sm += __shfl_xor(sm, 1);
            sm += __shfl_xor(sm, 2);
            float inv = 1.f / (sm + 1e-16f);
#pragma unroll
            for (int u = 0; u < 8; ++u) pk[base + t + 4 * u].x = __float_as_int(p[u] * inv);
        }
        __asm__ volatile("s_waitcnt lgkmcnt(0)" ::: "memory");
        __builtin_amdgcn_sched_barrier(0);
        // phase 3: lane = channels (2sl, 2sl+1) of its node; head = sl>>2
        int pbase = na * 273 + (sl >> 2) * 34;
        float acc0 = 0.f, acc1 = 0.f;
        int mdeg = max(degA, degB);
        for (int g = 0; g * 4 < mdeg; ++g) {
#pragma unroll
            for (int jj = 0; jj < 4; ++jj) {
                int j = g * 4 + jj;
                int2 p2 = pk[pbase + j];
                float w = __int_as_float(p2.x);
                unsigned hv = *(const unsigned*)&h1b[(size_t)p2.y * HOUT + 2 * sl];
                acc0 += w * b2f_lo(hv);
                acc1 += w * b2f_hi(hv);
            }
        }
        float2 bb = *(const float2*)&b1[2 * sl];
        float o0 = acc0 + bb.x, o1 = acc1 + bb.y;
        float e0 = o0 > 0.f ? o0 : expm1f(o0);
        float e1 = o1 > 0.f ? o1 : expm1f(o1);
        unsigned op = (unsigned)f2b(e0) | ((unsigned)f2b(e1) << 16);
        if (nodev) *(unsigned*)&hactb[(size_t)node * HOUT + 2 * sl] = op;
    } else {
        // rare fallback: serial online softmax per half, 2 channels per lane
        int hd = sl >> 2;
        float ad = nodev ? ad1[node * 8 + hd] : 0.f;
        float m = -1e30f, den = 0.f, a0 = 0.f, a1 = 0.f;
        int en = st + deg;
        for (int e = st; e < en; ++e) {
            int s = col[e];
            float e0 = as1[s * 8 + hd] + ad;
            float ee = e0 >= 0.f ? e0 : NEG * e0;
            unsigned hv = *(const unsigned*)&h1b[(size_t)s * HOUT + 2 * sl];
            float mn = fmaxf(m, ee);
            float sc = __expf(m - mn), p = __expf(ee - mn);
            den = den * sc + p;
            a0 = a0 * sc + p * b2f_lo(hv);
            a1 = a1 * sc + p * b2f_hi(hv);
            m = mn;
        }
        float2 bb = *(const float2*)&b1[2 * sl];
        float o0 = a0 / (den + 1e-16f) + bb.x;
        float o1 = a1 / (den + 1e-16f) + bb.y;
        float e0 = o0 > 0.f ? o0 : expm1f(o0);
        float e1 = o1 > 0.f ? o1 : expm1f(o1);
        unsigned op = (unsigned)f2b(e0) | ((unsigned)f2b(e1) << 16);
        if (nodev) *(unsigned*)&hactb[(size_t)node * HOUT + 2 * sl] = op;
    }
}

// ---------------- layer-2 GEMM (64->40) + attention dots: MFMA, no LDS ----------------

__global__ __launch_bounds__(256) void g2_k(const ushort* __restrict__ hactb, const ushort* __restrict__ W2t,
                                            const float* __restrict__ asw, const float* __restrict__ adw,
                                            ushort* __restrict__ h2b, float* __restrict__ as2,
                                            float* __restrict__ ad2, int n) {
    int tid = threadIdx.x;
    int lane = tid & 63, wid = tid >> 6;
    int lr = lane & 15, lg = lane >> 4;
    int row0 = blockIdx.x * 64 + wid * 16;
    if (row0 >= n) return;
    int gr = row0 + lr;
    bool vr = gr < n;
    f32x4 acc[3];
#pragma unroll
    for (int ct = 0; ct < 3; ++ct) acc[ct] = (f32x4){0.f, 0.f, 0.f, 0.f};
    const short8 z8 = (short8){0, 0, 0, 0, 0, 0, 0, 0};
#pragma unroll
    for (int ks = 0; ks < 2; ++ks) {
        short8 af = vr ? *(const short8*)&hactb[(size_t)gr * HOUT + ks * 32 + lg * 8] : z8;
#pragma unroll
        for (int ct = 0; ct < 3; ++ct) {
            short8 bf = *(const short8*)&W2t[(ct * 16 + lr) * HOUT + ks * 32 + lg * 8];
            acc[ct] = __builtin_amdgcn_mfma_f32_16x16x32_bf16(af, bf, acc[ct], 0, 0, 0);
        }
    }
    float av4[4], dv4[4];
#pragma unroll
    for (int q = 0; q < 4; ++q) {
        int r = row0 + lg * 4 + q;
        bool vw = r < n;
        float av = 0.f, dv = 0.f;
#pragma unroll
        for (int ct = 0; ct < 3; ++ct) {
            int c = ct * 16 + lr;
            if (c < NCLS) {
                float o = acc[ct][q];
                av += o * asw[c];
                dv += o * adw[c];
                if (vw) h2b[(size_t)r * NCLS + c] = f2b(o);
            }
        }
        av += __shfl_xor(av, 1); av += __shfl_xor(av, 2); av += __shfl_xor(av, 4); av += __shfl_xor(av, 8);
        dv += __shfl_xor(dv, 1); dv += __shfl_xor(dv, 2); dv += __shfl_xor(dv, 4); dv += __shfl_xor(dv, 8);
        av4[q] = av; dv4[q] = dv;
    }
#pragma unroll
    for (int q = 0; q < 4; ++q) {
        int r = row0 + lg * 4 + q;
        if (lr == q && r < n) as2[r] = av4[q];
        if (lr == 8 + q && r < n) ad2[r] = dv4[q];
    }
}

// ---------------- layer-2 aggregation + log_softmax: 2 nodes/wave ----------------
// 32 edge slots per half; channel phase: lanes sl<20 handle (2sl, 2sl+1).

__global__ __launch_bounds__(256) void l2agg_k(const ushort* __restrict__ h2b, const float* __restrict__ as2,
                                               const float* __restrict__ ad2, const float* __restrict__ b2,
                                               const int* __restrict__ rowptr, const int* __restrict__ col,
                                               float* __restrict__ out, int n) {
    __shared__ int2 pk_all[4][2 * 33];
    int wid = threadIdx.x >> 6, lane = threadIdx.x & 63;
    int nA = (blockIdx.x * 4 + wid) * 2;
    if (nA >= n) return;
    int nB = nA + 1;
    int na = lane >> 5, sl = lane & 31;
    int node = nA + na;
    bool nodev = node < n;
    int r0 = rowptr[nA];
    int r1 = rowptr[nA + 1];
    int r2 = (nB < n) ? rowptr[nB + 1] : r1;
    int degA = r1 - r0, degB = r2 - r1;
    int st  = na ? r1 : r0;
    int deg = na ? degB : degA;
    bool act = sl < 20;
    float z0, z1;

    if (degA <= 32 && degB <= 32) {
        int2* pk = pk_all[wid];
        bool v = nodev && (sl < deg);
        int s = 0; float av = 0.f;
        if (v) { s = col[st + sl]; av = as2[s]; }
        float ad = nodev ? ad2[node] : 0.f;
        float e0 = av + ad;
        float ee = v ? (e0 >= 0.f ? e0 : NEG * e0) : -1e30f;
        float m = ee;
        m = fmaxf(m, __shfl_xor(m, 1)); m = fmaxf(m, __shfl_xor(m, 2));
        m = fmaxf(m, __shfl_xor(m, 4)); m = fmaxf(m, __shfl_xor(m, 8));
        m = fmaxf(m, __shfl_xor(m, 16));
        float p = __expf(ee - m);
        float d = p;
        d += __shfl_xor(d, 1); d += __shfl_xor(d, 2); d += __shfl_xor(d, 4);
        d += __shfl_xor(d, 8); d += __shfl_xor(d, 16);
        float w = p / (d + 1e-16f);
        pk[na * 33 + sl] = make_int2(__float_as_int(w), s);
        __asm__ volatile("s_waitcnt lgkmcnt(0)" ::: "memory");
        __builtin_amdgcn_sched_barrier(0);
        float acc0 = 0.f, acc1 = 0.f;
        int mdeg = max(degA, degB);
        for (int g = 0; g * 4 < mdeg; ++g) {
#pragma unroll
            for (int jj = 0; jj < 4; ++jj) {
                int j = g * 4 + jj;
                int2 p2 = pk[na * 33 + j];
                float wv = __int_as_float(p2.x);
                if (act) {
                    unsigned hv = *(const unsigned*)&h2b[(size_t)p2.y * NCLS + 2 * sl];
                    acc0 += wv * b2f_lo(hv);
                    acc1 += wv * b2f_hi(hv);
                }
            }
        }
        if (act) {
            float2 bb = *(const float2*)&b2[2 * sl];
            z0 = acc0 + bb.x; z1 = acc1 + bb.y;
        } else { z0 = z1 = -1e30f; }
    } else {
        // rare fallback: serial online softmax per half
        float ad = nodev ? ad2[node] : 0.f;
        float m = -1e30f, den = 0.f, a0 = 0.f, a1 = 0.f;
        int en = st + deg;
        for (int e = st; e < en; ++e) {
            int s = col[e];
            float e0 = as2[s] + ad;
            float ee = e0 >= 0.f ? e0 : NEG * e0;
            float mn = fmaxf(m, ee);
            float sc = __expf(m - mn), p = __expf(ee - mn);
            den = den * sc + p;
            if (act) {
                unsigned hv = *(const unsigned*)&h2b[(size_t)s * NCLS + 2 * sl];
                a0 = a0 * sc + p * b2f_lo(hv);
                a1 = a1 * sc + p * b2f_hi(hv);
            }
            m = mn;
        }
        if (act) {
            float2 bb = *(const float2*)&b2[2 * sl];
            z0 = a0 / (den + 1e-16f) + bb.x;
            z1 = a1 / (den + 1e-16f) + bb.y;
        } else { z0 = z1 = -1e30f; }
    }
    // log_softmax over 40 classes (20 active lanes x 2), confined to each half
    float zm = fmaxf(z0, z1);
    zm = fmaxf(zm, __shfl_xor(zm, 1)); zm = fmaxf(zm, __shfl_xor(zm, 2));
    zm = fmaxf(zm, __shfl_xor(zm, 4)); zm = fmaxf(zm, __shfl_xor(zm, 8));
    zm = fmaxf(zm, __shfl_xor(zm, 16));
    float ex = act ? (__expf(z0 - zm) + __expf(z1 - zm)) : 0.f;
    ex += __shfl_xor(ex, 1); ex += __shfl_xor(ex, 2); ex += __shfl_xor(ex, 4);
    ex += __shfl_xor(ex, 8); ex += __shfl_xor(ex, 16);
    float ls = logf(ex);
    if (act && nodev) {
        float2 o = make_float2(z0 - zm - ls, z1 - zm - ls);
        *(float2*)&out[(size_t)node * NCLS + 2 * sl] = o;
    }
}

// ---------------- host ----------------

extern "C" void kernel_launch(void* const* d_in, const int* in_sizes, int n_in,
                              void* d_out, int out_size, void* d_ws, size_t ws_size,
                              hipStream_t stream) {
    const float* x    = (const float*)d_in[0];
    const int*   ei   = (const int*)d_in[1];
    const float* W1   = (const float*)d_in[2];
    const float* asw1 = (const float*)d_in[3];
    const float* adw1 = (const float*)d_in[4];
    const float* b1   = (const float*)d_in[5];
    const float* W2   = (const float*)d_in[6];
    const float* asw2 = (const float*)d_in[7];
    const float* adw2 = (const float*)d_in[8];
    const float* b2   = (const float*)d_in[9];
    float* out = (float*)d_out;

    const int n = in_sizes[0] / F_IN;          // 100000
    const int E = in_sizes[1] / 2;             // 1600000
    const int Etot = E + n;
    const int nbuck = (n + DPB - 1) / DPB;     // 391
    const int npair = (n + 1) / 2;

    char* ws = (char*)d_ws;
    size_t off = 0;
    auto alloc = [&](size_t bytes) -> void* {
        void* p = ws + off;
        off = (off + bytes + 255) & ~(size_t)255;
        return p;
    };
    int*    gcur   = (int*)alloc((size_t)nbuck * 4);
    int*    bbase  = (int*)alloc((size_t)nbuck * 4);
    int*    rowptr = (int*)alloc((size_t)(n + 1) * 4);
    int*    col    = (int*)alloc((size_t)Etot * 4);
    int2*   bkt    = (int2*)alloc((size_t)nbuck * CAP * 8);          // 25.2 MB
    ushort* h1b    = (ushort*)alloc((size_t)n * HOUT * 2);           // 12.8 MB (reused below)
    float*  as1    = (float*)alloc((size_t)n * HEADS * 4);
    float*  ad1    = (float*)alloc((size_t)n * HEADS * 4);
    ushort* hactb  = (ushort*)alloc((size_t)n * HOUT * 2);           // 12.8 MB
    ushort* Wtg    = (ushort*)alloc((size_t)HOUT * WLD * 2);         // 66.6 KB
    ushort* W2t    = (ushort*)alloc((size_t)48 * HOUT * 2);          // 6 KB
    ushort* h2b = h1b;
    float*  as2 = (float*)(h1b + (size_t)n * NCLS);
    float*  ad2 = as2 + n;

    init_k<<<(nbuck + 511) / 512, 512, 0, stream>>>(gcur, nbuck);
    passA_k<<<(Etot + 256 * EPT - 1) / (256 * EPT), 256, 0, stream>>>(ei, gcur, bkt, E, Etot, nbuck);
    bscan_k<<<1, 512, 0, stream>>>(gcur, bbase, rowptr, nbuck, n, Etot);
    passB_k<<<nbuck, 256, 0, stream>>>(bkt, gcur, bbase, rowptr, col, n);

    wconv_k<<<(F_IN * HOUT + 255) / 256, 256, 0, stream>>>(W1, Wtg);
    w2conv_k<<<(48 * HOUT + 255) / 256, 256, 0, stream>>>(W2, W2t);
    gemm1_k<<<(n + 127) / 128, 256, 0, stream>>>(x, Wtg, h1b, n);
    att1_k<<<(n * HEADS + 255) / 256, 256, 0, stream>>>(h1b, asw1, adw1, as1, ad1, n);
    l1agg_k<<<(npair + 3) / 4, 256, 0, stream>>>(h1b, as1, ad1, b1, rowptr, col, hactb, n);
    g2_k<<<(n + 63) / 64, 256, 0, stream>>>(hactb, W2t, asw2, adw2, h2b, as2, ad2, n);
    l2agg_k<<<(npair + 3) / 4, 256, 0, stream>>>(h2b, as2, ad2, b2, rowptr, col, out, n);
}